// Round 1
// baseline (6510.791 us; speedup 1.0000x reference)
//
#include <hip/hip_runtime.h>
#include <math.h>

// Problem constants (from reference): F=IN_FEATS=H2=128, C=N_CLASSES=64, G=N_GRAPHS=128
#define F 128
#define C 64
#define G 128
#define TM 32   // rows per block in gemm_epi_kernel; N (100000) % 32 == 0

__device__ __forceinline__ void atomicAddF(float* p, float v) {
  // relaxed agent-scope fadd -> global_atomic_add_f32 (no CAS loop)
  __hip_atomic_fetch_add(p, v, __ATOMIC_RELAXED, __HIP_MEMORY_SCOPE_AGENT);
}

// ---------------- degree counting ----------------
__global__ void deg_kernel(const int* __restrict__ src, const int* __restrict__ dst,
                           int* __restrict__ dego, int* __restrict__ degi, int E) {
  int i = blockIdx.x * blockDim.x + threadIdx.x;
  if (i < E) {
    atomicAdd(&dego[src[i]], 1);
    atomicAdd(&degi[dst[i]], 1);
  }
}

// ---------------- deg^-1/2 + per-graph node counts ----------------
__global__ void dnorm_kernel(const int* __restrict__ dego, const int* __restrict__ degi,
                             const int* __restrict__ gid,
                             float* __restrict__ dno, float* __restrict__ dni,
                             int* __restrict__ cnt, int N) {
  int i = blockIdx.x * blockDim.x + threadIdx.x;
  if (i < N) {
    int a = dego[i]; if (a < 1) a = 1;
    int b = degi[i]; if (b < 1) b = 1;
    dno[i] = 1.0f / sqrtf((float)a);
    dni[i] = 1.0f / sqrtf((float)b);
    atomicAdd(&cnt[gid[i]], 1);
  }
}

// ---------------- edge scatter-add: agg[dst] += feat[src] * dno[src] ----------------
// 32 lanes per edge, one float4 per lane (128 floats/row).
__global__ __launch_bounds__(256) void edge_agg_kernel(
    const int* __restrict__ src, const int* __restrict__ dst,
    const float* __restrict__ feat, const float* __restrict__ dno,
    float* __restrict__ agg, int E) {
  int grp = blockIdx.x * 8 + (threadIdx.x >> 5);
  int l = threadIdx.x & 31;
  if (grp >= E) return;
  int s = src[grp];
  int d = dst[grp];
  float dn = dno[s];
  float4 v = ((const float4*)(feat + (size_t)s * F))[l];
  float* a = agg + (size_t)d * F + l * 4;
  atomicAddF(a + 0, v.x * dn);
  atomicAddF(a + 1, v.y * dn);
  atomicAddF(a + 2, v.z * dn);
  atomicAddF(a + 3, v.w * dn);
}

// ---------------- fused: h = agg@W * dni + b; L2-normalize row; sigmoid; hg[gid] += h ----------
// Block: 256 threads = 8 row-groups (4 rows each) x 32 col-groups (4 cols each).
// LDS: full W (64KB) + A tile (16KB).
__global__ __launch_bounds__(256) void gemm_epi_kernel(
    const float* __restrict__ agg, const float* __restrict__ Wg,
    const float* __restrict__ bg, const float* __restrict__ dni,
    const int* __restrict__ gid, float* __restrict__ hg, int N) {
  __shared__ float Wl[F * F];
  __shared__ float Al[TM * F];
  int tid = threadIdx.x;

  const float4* Wv = (const float4*)Wg;
  float4* Wlv = (float4*)Wl;
#pragma unroll
  for (int i = 0; i < (F * F / 4) / 256; ++i)
    Wlv[tid + i * 256] = Wv[tid + i * 256];

  int r0 = blockIdx.x * TM;
  const float4* Av = (const float4*)(agg + (size_t)r0 * F);
  float4* Alv = (float4*)Al;
#pragma unroll
  for (int i = 0; i < (TM * F / 4) / 256; ++i)
    Alv[tid + i * 256] = Av[tid + i * 256];
  __syncthreads();

  int rg = tid >> 5;   // 0..7  (4 rows each)
  int cg = tid & 31;   // 0..31 (4 cols each)

  float acc[4][4];
#pragma unroll
  for (int i = 0; i < 4; ++i)
#pragma unroll
    for (int j = 0; j < 4; ++j) acc[i][j] = 0.0f;

  for (int k0 = 0; k0 < F; k0 += 4) {
    float4 a4[4];
#pragma unroll
    for (int i = 0; i < 4; ++i)
      a4[i] = *(const float4*)&Al[(rg * 4 + i) * F + k0];
#pragma unroll
    for (int kk = 0; kk < 4; ++kk) {
      float4 wv = *(const float4*)&Wl[(k0 + kk) * F + cg * 4];
#pragma unroll
      for (int i = 0; i < 4; ++i) {
        float av = ((const float*)&a4[i])[kk];
        acc[i][0] += av * wv.x;
        acc[i][1] += av * wv.y;
        acc[i][2] += av * wv.z;
        acc[i][3] += av * wv.w;
      }
    }
  }

  // epilogue
  float dnr[4];
  int gg[4];
#pragma unroll
  for (int i = 0; i < 4; ++i) {
    int r = r0 + rg * 4 + i;
    dnr[i] = dni[r];
    gg[i] = gid[r];
  }
  float4 bb = *(const float4*)(bg + cg * 4);
  const float* bbf = (const float*)&bb;

  float y[4][4], ssq[4];
#pragma unroll
  for (int i = 0; i < 4; ++i) {
    ssq[i] = 0.0f;
#pragma unroll
    for (int j = 0; j < 4; ++j) {
      float t = acc[i][j] * dnr[i] + bbf[j];
      y[i][j] = t;
      ssq[i] += t * t;
    }
  }
  // reduce ssq across the 32 col-group lanes (lane bits 0..4)
#pragma unroll
  for (int m = 1; m < 32; m <<= 1) {
#pragma unroll
    for (int i = 0; i < 4; ++i) ssq[i] += __shfl_xor(ssq[i], m);
  }

  float u[4][4];
#pragma unroll
  for (int i = 0; i < 4; ++i) {
    float inv = 1.0f / fmaxf(sqrtf(ssq[i]), 1e-12f);
#pragma unroll
    for (int j = 0; j < 4; ++j)
      u[i][j] = 1.0f / (1.0f + expf(-y[i][j] * inv));  // relu(sigmoid(x)) == sigmoid(x)
  }

  // per-graph accumulation; gid sorted -> waves nearly always uniform
  int lane = tid & 63;
  int wv_id = tid >> 6;             // wave covers rows r0+8*wv_id .. +7
  int g0 = gid[r0 + wv_id * 8];
  bool ok = (gg[0] == g0) && (gg[1] == g0) && (gg[2] == g0) && (gg[3] == g0);
  if (__all(ok)) {
    float cs[4];
#pragma unroll
    for (int j = 0; j < 4; ++j) {
      cs[j] = u[0][j] + u[1][j] + u[2][j] + u[3][j];
      cs[j] += __shfl_xor(cs[j], 32);   // add partner row-group (8 rows total)
    }
    if (lane < 32) {
#pragma unroll
      for (int j = 0; j < 4; ++j)
        atomicAddF(&hg[(size_t)g0 * F + cg * 4 + j], cs[j]);
    }
  } else {
#pragma unroll
    for (int i = 0; i < 4; ++i)
#pragma unroll
      for (int j = 0; j < 4; ++j)
        atomicAddF(&hg[(size_t)gg[i] * F + cg * 4 + j], u[i][j]);
  }
}

// ---------------- final: z = (hg/cnt)@Wc + bc per branch; out[g] = ||z1-z2+1e-6|| ----------------
__global__ __launch_bounds__(64) void final_kernel(
    const float* __restrict__ hg1, const int* __restrict__ cnt1,
    const float* __restrict__ hg2, const int* __restrict__ cnt2,
    const float* __restrict__ Wc, const float* __restrict__ bc,
    float* __restrict__ out) {
  __shared__ float v1[F], v2[F];
  int g = blockIdx.x, c = threadIdx.x;
  float ic1 = 1.0f / fmaxf((float)cnt1[g], 1.0f);
  float ic2 = 1.0f / fmaxf((float)cnt2[g], 1.0f);
  for (int i = c; i < F; i += 64) {
    v1[i] = hg1[(size_t)g * F + i] * ic1;
    v2[i] = hg2[(size_t)g * F + i] * ic2;
  }
  __syncthreads();
  float z1 = bc[c], z2 = bc[c];
  for (int k = 0; k < F; ++k) {
    float w = Wc[k * C + c];
    z1 += v1[k] * w;
    z2 += v2[k] * w;
  }
  float d = z1 - z2 + 1e-6f;
  d *= d;
#pragma unroll
  for (int m = 1; m < 64; m <<= 1) d += __shfl_xor(d, m);
  if (c == 0) out[g] = sqrtf(d);
}

extern "C" void kernel_launch(void* const* d_in, const int* in_sizes, int n_in,
                              void* d_out, int out_size, void* d_ws, size_t ws_size,
                              hipStream_t stream) {
  const float* feat1 = (const float*)d_in[0];
  const float* feat2 = (const float*)d_in[1];
  const int* src1 = (const int*)d_in[2];
  const int* dst1 = (const int*)d_in[3];
  const int* gid1 = (const int*)d_in[4];
  const int* src2 = (const int*)d_in[5];
  const int* dst2 = (const int*)d_in[6];
  const int* gid2 = (const int*)d_in[7];
  const float* Wg = (const float*)d_in[8];
  const float* bg = (const float*)d_in[9];
  const float* Wc = (const float*)d_in[10];
  const float* bc = (const float*)d_in[11];
  float* out = (float*)d_out;

  int N = in_sizes[0] / F;
  int E = in_sizes[2];

  // ---- workspace layout (zero-init region first) ----
  char* w = (char*)d_ws;
  float* agg1 = (float*)w; w += (size_t)N * F * 4;
  float* agg2 = (float*)w; w += (size_t)N * F * 4;
  float* hg1  = (float*)w; w += (size_t)G * F * 4;
  float* hg2  = (float*)w; w += (size_t)G * F * 4;
  int* dego1 = (int*)w; w += (size_t)N * 4;
  int* degi1 = (int*)w; w += (size_t)N * 4;
  int* dego2 = (int*)w; w += (size_t)N * 4;
  int* degi2 = (int*)w; w += (size_t)N * 4;
  int* cnt1 = (int*)w; w += G * 4;
  int* cnt2 = (int*)w; w += G * 4;
  size_t zbytes = (size_t)(w - (char*)d_ws);
  float* dno1 = (float*)w; w += (size_t)N * 4;
  float* dni1 = (float*)w; w += (size_t)N * 4;
  float* dno2 = (float*)w; w += (size_t)N * 4;
  float* dni2 = (float*)w; w += (size_t)N * 4;
  if ((size_t)(w - (char*)d_ws) > ws_size) return;  // workspace too small: fail loudly

  hipMemsetAsync(d_ws, 0, zbytes, stream);

  int eb = (E + 255) / 256;
  deg_kernel<<<eb, 256, 0, stream>>>(src1, dst1, dego1, degi1, E);
  deg_kernel<<<eb, 256, 0, stream>>>(src2, dst2, dego2, degi2, E);

  int nb = (N + 255) / 256;
  dnorm_kernel<<<nb, 256, 0, stream>>>(dego1, degi1, gid1, dno1, dni1, cnt1, N);
  dnorm_kernel<<<nb, 256, 0, stream>>>(dego2, degi2, gid2, dno2, dni2, cnt2, N);

  int egb = (E + 7) / 8;
  edge_agg_kernel<<<egb, 256, 0, stream>>>(src1, dst1, feat1, dno1, agg1, E);
  edge_agg_kernel<<<egb, 256, 0, stream>>>(src2, dst2, feat2, dno2, agg2, E);

  int gb = N / TM;
  gemm_epi_kernel<<<gb, 256, 0, stream>>>(agg1, Wg, bg, dni1, gid1, hg1, N);
  gemm_epi_kernel<<<gb, 256, 0, stream>>>(agg2, Wg, bg, dni2, gid2, hg2, N);

  final_kernel<<<G, 64, 0, stream>>>(hg1, cnt1, hg2, cnt2, Wc, bc, out);
}

// Round 2
// 1621.466 us; speedup vs baseline: 4.0154x; 4.0154x over previous
//
#include <hip/hip_runtime.h>
#include <math.h>

// Problem constants: F=IN_FEATS=H2=128, C=N_CLASSES=64, G=N_GRAPHS=128
#define F 128
#define C 64
#define G 128
#define TM 32     // rows per block in gemm_epi_kernel; N (100000) % 32 == 0
#define SCHUNK 1024

__device__ __forceinline__ void atomicAddF(float* p, float v) {
  __hip_atomic_fetch_add(p, v, __ATOMIC_RELAXED, __HIP_MEMORY_SCOPE_AGENT);
}

// ---------------- degree counting ----------------
__global__ void deg_kernel(const int* __restrict__ src, const int* __restrict__ dst,
                           int* __restrict__ dego, int* __restrict__ degi, int E) {
  int i = blockIdx.x * blockDim.x + threadIdx.x;
  if (i < E) {
    atomicAdd(&dego[src[i]], 1);
    atomicAdd(&degi[dst[i]], 1);
  }
}

// ---------------- deg^-1/2 + per-graph node counts ----------------
__global__ void dnorm_kernel(const int* __restrict__ dego, const int* __restrict__ degi,
                             const int* __restrict__ gid,
                             float* __restrict__ dno, float* __restrict__ dni,
                             int* __restrict__ cnt, int N) {
  int i = blockIdx.x * blockDim.x + threadIdx.x;
  if (i < N) {
    int a = dego[i]; if (a < 1) a = 1;
    int b = degi[i]; if (b < 1) b = 1;
    dno[i] = 1.0f / sqrtf((float)a);
    dni[i] = 1.0f / sqrtf((float)b);
    atomicAdd(&cnt[gid[i]], 1);
  }
}

// ---------------- exclusive scan of degi -> cursor (3 phases) ----------------
__global__ __launch_bounds__(256) void scanA_kernel(const int* __restrict__ deg,
                                                    int* __restrict__ bsum, int N) {
  int b = blockIdx.x, t = threadIdx.x;
  int base = b * SCHUNK;
  int v = 0;
  for (int i = t; i < SCHUNK; i += 256) {
    int idx = base + i;
    if (idx < N) v += deg[idx];
  }
#pragma unroll
  for (int m = 1; m < 64; m <<= 1) v += __shfl_xor(v, m);
  __shared__ int ws[4];
  if ((t & 63) == 0) ws[t >> 6] = v;
  __syncthreads();
  if (t == 0) bsum[b] = ws[0] + ws[1] + ws[2] + ws[3];
}

// single block, NB <= 256; in-place exclusive scan
__global__ __launch_bounds__(256) void scanB_kernel(int* __restrict__ bsum, int NB) {
  __shared__ int s[256];
  int t = threadIdx.x;
  int v = (t < NB) ? bsum[t] : 0;
  s[t] = v;
  __syncthreads();
  for (int off = 1; off < 256; off <<= 1) {
    int x = (t >= off) ? s[t - off] : 0;
    __syncthreads();
    s[t] += x;
    __syncthreads();
  }
  if (t < NB) bsum[t] = s[t] - v;
}

__global__ __launch_bounds__(256) void scanC_kernel(const int* __restrict__ deg,
                                                    const int* __restrict__ bsum,
                                                    int* __restrict__ cursor, int N) {
  int b = blockIdx.x, t = threadIdx.x;
  int base = b * SCHUNK + t * 4;
  int d[4];
#pragma unroll
  for (int i = 0; i < 4; ++i) {
    int idx = base + i;
    d[i] = (idx < N) ? deg[idx] : 0;
  }
  int p0 = 0, p1 = d[0], p2 = d[0] + d[1], p3 = d[0] + d[1] + d[2];
  int tot = p3 + d[3];
  __shared__ int sh[256];
  sh[t] = tot;
  __syncthreads();
  for (int off = 1; off < 256; off <<= 1) {
    int x = (t >= off) ? sh[t - off] : 0;
    __syncthreads();
    sh[t] += x;
    __syncthreads();
  }
  int texcl = sh[t] - tot;
  int off0 = bsum[b] + texcl;
  int p[4] = {p0, p1, p2, p3};
#pragma unroll
  for (int i = 0; i < 4; ++i) {
    int idx = base + i;
    if (idx < N) cursor[idx] = off0 + p[i];
  }
}

// ---------------- counting-sort scatter: esrc bucketed by dst ----------------
// After this kernel, cursor[d] == start(d) + degi[d]; reduce recovers start = cursor - degi.
__global__ __launch_bounds__(256) void scatter_kernel(const int* __restrict__ src,
                                                      const int* __restrict__ dst,
                                                      int* __restrict__ cursor,
                                                      int* __restrict__ esrc, int E) {
  int i = blockIdx.x * blockDim.x + threadIdx.x;
  if (i < E) {
    int pos = atomicAdd(&cursor[dst[i]], 1);
    esrc[pos] = src[i];
  }
}

// ---------------- gather-reduce: agg[d] = sum over in-edges of feat[s]*dno[s] ----------
// 32 lanes per dst node; batched index loads + shfl broadcast; float4 row gathers.
__global__ __launch_bounds__(256) void gather_reduce_kernel(
    const int* __restrict__ esrc, const int* __restrict__ cursor,
    const int* __restrict__ degi, const float* __restrict__ dno,
    const float* __restrict__ feat, float* __restrict__ agg, int N) {
  int node = blockIdx.x * 8 + (threadIdx.x >> 5);
  int l = threadIdx.x & 31;
  if (node >= N) return;
  int cnt = degi[node];
  int start = cursor[node] - cnt;
  float4 acc = {0.f, 0.f, 0.f, 0.f};
  for (int j0 = 0; j0 < cnt; j0 += 32) {
    int nb = cnt - j0; if (nb > 32) nb = 32;
    int myi = (l < nb) ? esrc[start + j0 + l] : 0;
    float mydn = dno[myi];
#pragma unroll 4
    for (int k = 0; k < nb; ++k) {
      int s = __shfl(myi, k, 32);
      float dn = __shfl(mydn, k, 32);
      float4 v = ((const float4*)(feat + (size_t)s * F))[l];
      acc.x = fmaf(v.x, dn, acc.x);
      acc.y = fmaf(v.y, dn, acc.y);
      acc.z = fmaf(v.z, dn, acc.z);
      acc.w = fmaf(v.w, dn, acc.w);
    }
  }
  ((float4*)(agg + (size_t)node * F))[l] = acc;
}

// ---------------- fused: h = agg@W * dni + b; L2-normalize; sigmoid; hg[gid] += h ----------
__global__ __launch_bounds__(256) void gemm_epi_kernel(
    const float* __restrict__ agg, const float* __restrict__ Wg,
    const float* __restrict__ bg, const float* __restrict__ dni,
    const int* __restrict__ gid, float* __restrict__ hg, int N) {
  __shared__ float Wl[F * F];
  __shared__ float Al[TM * F];
  int tid = threadIdx.x;

  const float4* Wv = (const float4*)Wg;
  float4* Wlv = (float4*)Wl;
#pragma unroll
  for (int i = 0; i < (F * F / 4) / 256; ++i)
    Wlv[tid + i * 256] = Wv[tid + i * 256];

  int r0 = blockIdx.x * TM;
  const float4* Av = (const float4*)(agg + (size_t)r0 * F);
  float4* Alv = (float4*)Al;
#pragma unroll
  for (int i = 0; i < (TM * F / 4) / 256; ++i)
    Alv[tid + i * 256] = Av[tid + i * 256];
  __syncthreads();

  int rg = tid >> 5;   // 0..7  (4 rows each)
  int cg = tid & 31;   // 0..31 (4 cols each)

  float acc[4][4];
#pragma unroll
  for (int i = 0; i < 4; ++i)
#pragma unroll
    for (int j = 0; j < 4; ++j) acc[i][j] = 0.0f;

  for (int k0 = 0; k0 < F; k0 += 4) {
    float4 a4[4];
#pragma unroll
    for (int i = 0; i < 4; ++i)
      a4[i] = *(const float4*)&Al[(rg * 4 + i) * F + k0];
#pragma unroll
    for (int kk = 0; kk < 4; ++kk) {
      float4 wv = *(const float4*)&Wl[(k0 + kk) * F + cg * 4];
#pragma unroll
      for (int i = 0; i < 4; ++i) {
        float av = ((const float*)&a4[i])[kk];
        acc[i][0] += av * wv.x;
        acc[i][1] += av * wv.y;
        acc[i][2] += av * wv.z;
        acc[i][3] += av * wv.w;
      }
    }
  }

  float dnr[4];
  int gg[4];
#pragma unroll
  for (int i = 0; i < 4; ++i) {
    int r = r0 + rg * 4 + i;
    dnr[i] = dni[r];
    gg[i] = gid[r];
  }
  float4 bb = *(const float4*)(bg + cg * 4);
  const float* bbf = (const float*)&bb;

  float y[4][4], ssq[4];
#pragma unroll
  for (int i = 0; i < 4; ++i) {
    ssq[i] = 0.0f;
#pragma unroll
    for (int j = 0; j < 4; ++j) {
      float t = acc[i][j] * dnr[i] + bbf[j];
      y[i][j] = t;
      ssq[i] += t * t;
    }
  }
#pragma unroll
  for (int m = 1; m < 32; m <<= 1) {
#pragma unroll
    for (int i = 0; i < 4; ++i) ssq[i] += __shfl_xor(ssq[i], m);
  }

  float u[4][4];
#pragma unroll
  for (int i = 0; i < 4; ++i) {
    float inv = 1.0f / fmaxf(sqrtf(ssq[i]), 1e-12f);
#pragma unroll
    for (int j = 0; j < 4; ++j)
      u[i][j] = 1.0f / (1.0f + expf(-y[i][j] * inv));  // relu(sigmoid(x)) == sigmoid(x)
  }

  int lane = tid & 63;
  int wv_id = tid >> 6;
  int g0 = gid[r0 + wv_id * 8];
  bool ok = (gg[0] == g0) && (gg[1] == g0) && (gg[2] == g0) && (gg[3] == g0);
  if (__all(ok)) {
    float cs[4];
#pragma unroll
    for (int j = 0; j < 4; ++j) {
      cs[j] = u[0][j] + u[1][j] + u[2][j] + u[3][j];
      cs[j] += __shfl_xor(cs[j], 32);
    }
    if (lane < 32) {
#pragma unroll
      for (int j = 0; j < 4; ++j)
        atomicAddF(&hg[(size_t)g0 * F + cg * 4 + j], cs[j]);
    }
  } else {
#pragma unroll
    for (int i = 0; i < 4; ++i)
#pragma unroll
      for (int j = 0; j < 4; ++j)
        atomicAddF(&hg[(size_t)gg[i] * F + cg * 4 + j], u[i][j]);
  }
}

// ---------------- final ----------------
__global__ __launch_bounds__(64) void final_kernel(
    const float* __restrict__ hg1, const int* __restrict__ cnt1,
    const float* __restrict__ hg2, const int* __restrict__ cnt2,
    const float* __restrict__ Wc, const float* __restrict__ bc,
    float* __restrict__ out) {
  __shared__ float v1[F], v2[F];
  int g = blockIdx.x, c = threadIdx.x;
  float ic1 = 1.0f / fmaxf((float)cnt1[g], 1.0f);
  float ic2 = 1.0f / fmaxf((float)cnt2[g], 1.0f);
  for (int i = c; i < F; i += 64) {
    v1[i] = hg1[(size_t)g * F + i] * ic1;
    v2[i] = hg2[(size_t)g * F + i] * ic2;
  }
  __syncthreads();
  float z1 = bc[c], z2 = bc[c];
  for (int k = 0; k < F; ++k) {
    float w = Wc[k * C + c];
    z1 += v1[k] * w;
    z2 += v2[k] * w;
  }
  float d = z1 - z2 + 1e-6f;
  d *= d;
#pragma unroll
  for (int m = 1; m < 64; m <<= 1) d += __shfl_xor(d, m);
  if (c == 0) out[g] = sqrtf(d);
}

extern "C" void kernel_launch(void* const* d_in, const int* in_sizes, int n_in,
                              void* d_out, int out_size, void* d_ws, size_t ws_size,
                              hipStream_t stream) {
  const float* feat1 = (const float*)d_in[0];
  const float* feat2 = (const float*)d_in[1];
  const int* src1 = (const int*)d_in[2];
  const int* dst1 = (const int*)d_in[3];
  const int* gid1 = (const int*)d_in[4];
  const int* src2 = (const int*)d_in[5];
  const int* dst2 = (const int*)d_in[6];
  const int* gid2 = (const int*)d_in[7];
  const float* Wg = (const float*)d_in[8];
  const float* bg = (const float*)d_in[9];
  const float* Wc = (const float*)d_in[10];
  const float* bc = (const float*)d_in[11];
  float* out = (float*)d_out;

  int N = in_sizes[0] / F;
  int E = in_sizes[2];
  int NB = (N + SCHUNK - 1) / SCHUNK;   // scan blocks (98 for N=100000)

  // ---- workspace layout: zero-init region first ----
  char* w = (char*)d_ws;
  int* dego1 = (int*)w; w += (size_t)N * 4;
  int* degi1 = (int*)w; w += (size_t)N * 4;
  int* dego2 = (int*)w; w += (size_t)N * 4;
  int* degi2 = (int*)w; w += (size_t)N * 4;
  int* cnt1 = (int*)w; w += G * 4;
  int* cnt2 = (int*)w; w += G * 4;
  float* hg1 = (float*)w; w += (size_t)G * F * 4;
  float* hg2 = (float*)w; w += (size_t)G * F * 4;
  size_t zbytes = (size_t)(w - (char*)d_ws);
  // non-zeroed scratch:
  float* agg1 = (float*)w; w += (size_t)N * F * 4;
  float* agg2 = (float*)w; w += (size_t)N * F * 4;
  float* dno1 = (float*)w; w += (size_t)N * 4;
  float* dni1 = (float*)w; w += (size_t)N * 4;
  float* dno2 = (float*)w; w += (size_t)N * 4;
  float* dni2 = (float*)w; w += (size_t)N * 4;
  int* cursor1 = (int*)w; w += (size_t)N * 4;
  int* cursor2 = (int*)w; w += (size_t)N * 4;
  int* esrc1 = (int*)w; w += (size_t)E * 4;
  int* esrc2 = (int*)w; w += (size_t)E * 4;
  int* bsum1 = (int*)w; w += 256 * 4;
  int* bsum2 = (int*)w; w += 256 * 4;
  if ((size_t)(w - (char*)d_ws) > ws_size) return;  // fail loudly (output stays poisoned)

  hipMemsetAsync(d_ws, 0, zbytes, stream);

  int eb = (E + 255) / 256;
  deg_kernel<<<eb, 256, 0, stream>>>(src1, dst1, dego1, degi1, E);
  deg_kernel<<<eb, 256, 0, stream>>>(src2, dst2, dego2, degi2, E);

  int nb = (N + 255) / 256;
  dnorm_kernel<<<nb, 256, 0, stream>>>(dego1, degi1, gid1, dno1, dni1, cnt1, N);
  dnorm_kernel<<<nb, 256, 0, stream>>>(dego2, degi2, gid2, dno2, dni2, cnt2, N);

  // exclusive scan of degi -> cursor
  scanA_kernel<<<NB, 256, 0, stream>>>(degi1, bsum1, N);
  scanA_kernel<<<NB, 256, 0, stream>>>(degi2, bsum2, N);
  scanB_kernel<<<1, 256, 0, stream>>>(bsum1, NB);
  scanB_kernel<<<1, 256, 0, stream>>>(bsum2, NB);
  scanC_kernel<<<NB, 256, 0, stream>>>(degi1, bsum1, cursor1, N);
  scanC_kernel<<<NB, 256, 0, stream>>>(degi2, bsum2, cursor2, N);

  // counting-sort scatter of src indices bucketed by dst
  scatter_kernel<<<eb, 256, 0, stream>>>(src1, dst1, cursor1, esrc1, E);
  scatter_kernel<<<eb, 256, 0, stream>>>(src2, dst2, cursor2, esrc2, E);

  // gather-reduce into agg (writes every row exactly once; no memset needed)
  int gbr = (N + 7) / 8;
  gather_reduce_kernel<<<gbr, 256, 0, stream>>>(esrc1, cursor1, degi1, dno1, feat1, agg1, N);
  gather_reduce_kernel<<<gbr, 256, 0, stream>>>(esrc2, cursor2, degi2, dno2, feat2, agg2, N);

  int gb = N / TM;
  gemm_epi_kernel<<<gb, 256, 0, stream>>>(agg1, Wg, bg, dni1, gid1, hg1, N);
  gemm_epi_kernel<<<gb, 256, 0, stream>>>(agg2, Wg, bg, dni2, gid2, hg2, N);

  final_kernel<<<G, 64, 0, stream>>>(hg1, cnt1, hg2, cnt2, Wc, bc, out);
}

// Round 3
// 1085.946 us; speedup vs baseline: 5.9955x; 1.4931x over previous
//
#include <hip/hip_runtime.h>
#include <math.h>

// Problem constants: F=IN_FEATS=H2=128, C=N_CLASSES=64, G=N_GRAPHS=128
#define F 128
#define C 64
#define G 128
#define TM 32     // rows per block in gemm_epi_kernel; N (100000) % 32 == 0
#define SCHUNK 1024

__device__ __forceinline__ void atomicAddF(float* p, float v) {
  __hip_atomic_fetch_add(p, v, __ATOMIC_RELAXED, __HIP_MEMORY_SCOPE_AGENT);
}

// ---------------- degree counting (both branches, blockIdx.y selects) ----------------
__global__ void deg_kernel(const int* __restrict__ src1, const int* __restrict__ dst1,
                           const int* __restrict__ src2, const int* __restrict__ dst2,
                           int* __restrict__ dego1, int* __restrict__ degi1,
                           int* __restrict__ dego2, int* __restrict__ degi2, int E) {
  const int* src = blockIdx.y ? src2 : src1;
  const int* dst = blockIdx.y ? dst2 : dst1;
  int* dego = blockIdx.y ? dego2 : dego1;
  int* degi = blockIdx.y ? degi2 : degi1;
  int i = blockIdx.x * blockDim.x + threadIdx.x;
  if (i < E) {
    atomicAdd(&dego[src[i]], 1);
    atomicAdd(&degi[dst[i]], 1);
  }
}

// ---------------- deg^-1/2 (pure elementwise now) ----------------
__global__ void dnorm_kernel(const int* __restrict__ dego1, const int* __restrict__ degi1,
                             const int* __restrict__ dego2, const int* __restrict__ degi2,
                             float* __restrict__ dno1, float* __restrict__ dni1,
                             float* __restrict__ dno2, float* __restrict__ dni2, int N) {
  const int* dego = blockIdx.y ? dego2 : dego1;
  const int* degi = blockIdx.y ? degi2 : degi1;
  float* dno = blockIdx.y ? dno2 : dno1;
  float* dni = blockIdx.y ? dni2 : dni1;
  int i = blockIdx.x * blockDim.x + threadIdx.x;
  if (i < N) {
    int a = dego[i]; if (a < 1) a = 1;
    int b = degi[i]; if (b < 1) b = 1;
    dno[i] = 1.0f / sqrtf((float)a);
    dni[i] = 1.0f / sqrtf((float)b);
  }
}

// ---------------- per-graph node counts via binary search (gid is sorted) ----------------
__global__ __launch_bounds__(128) void cnt_kernel(const int* __restrict__ gid1,
                                                  const int* __restrict__ gid2,
                                                  int* __restrict__ cnt1,
                                                  int* __restrict__ cnt2, int N) {
  const int* gid = blockIdx.x ? gid2 : gid1;
  int* cnt = blockIdx.x ? cnt2 : cnt1;
  int g = threadIdx.x;
  int lo = 0, hi = N;
  while (lo < hi) { int m = (lo + hi) >> 1; if (gid[m] < g) lo = m + 1; else hi = m; }
  int lo2 = lo, hi2 = N;
  while (lo2 < hi2) { int m = (lo2 + hi2) >> 1; if (gid[m] <= g) lo2 = m + 1; else hi2 = m; }
  cnt[g] = lo2 - lo;
}

// ---------------- exclusive scan of degi -> cursor (3 phases) ----------------
__global__ __launch_bounds__(256) void scanA_kernel(const int* __restrict__ deg,
                                                    int* __restrict__ bsum, int N) {
  int b = blockIdx.x, t = threadIdx.x;
  int base = b * SCHUNK;
  int v = 0;
  for (int i = t; i < SCHUNK; i += 256) {
    int idx = base + i;
    if (idx < N) v += deg[idx];
  }
#pragma unroll
  for (int m = 1; m < 64; m <<= 1) v += __shfl_xor(v, m);
  __shared__ int ws[4];
  if ((t & 63) == 0) ws[t >> 6] = v;
  __syncthreads();
  if (t == 0) bsum[b] = ws[0] + ws[1] + ws[2] + ws[3];
}

__global__ __launch_bounds__(256) void scanB_kernel(int* __restrict__ bsum, int NB) {
  __shared__ int s[256];
  int t = threadIdx.x;
  int v = (t < NB) ? bsum[t] : 0;
  s[t] = v;
  __syncthreads();
  for (int off = 1; off < 256; off <<= 1) {
    int x = (t >= off) ? s[t - off] : 0;
    __syncthreads();
    s[t] += x;
    __syncthreads();
  }
  if (t < NB) bsum[t] = s[t] - v;
}

__global__ __launch_bounds__(256) void scanC_kernel(const int* __restrict__ deg,
                                                    const int* __restrict__ bsum,
                                                    int* __restrict__ cursor, int N) {
  int b = blockIdx.x, t = threadIdx.x;
  int base = b * SCHUNK + t * 4;
  int d[4];
#pragma unroll
  for (int i = 0; i < 4; ++i) {
    int idx = base + i;
    d[i] = (idx < N) ? deg[idx] : 0;
  }
  int p1 = d[0], p2 = d[0] + d[1], p3 = d[0] + d[1] + d[2];
  int tot = p3 + d[3];
  __shared__ int sh[256];
  sh[t] = tot;
  __syncthreads();
  for (int off = 1; off < 256; off <<= 1) {
    int x = (t >= off) ? sh[t - off] : 0;
    __syncthreads();
    sh[t] += x;
    __syncthreads();
  }
  int texcl = sh[t] - tot;
  int off0 = bsum[b] + texcl;
  int p[4] = {0, p1, p2, p3};
#pragma unroll
  for (int i = 0; i < 4; ++i) {
    int idx = base + i;
    if (idx < N) cursor[idx] = off0 + p[i];
  }
}

// ---------------- counting-sort scatter: esrc bucketed by dst ----------------
__global__ __launch_bounds__(256) void scatter_kernel(
    const int* __restrict__ src1, const int* __restrict__ dst1,
    const int* __restrict__ src2, const int* __restrict__ dst2,
    int* __restrict__ cursor1, int* __restrict__ cursor2,
    int* __restrict__ esrc1, int* __restrict__ esrc2, int E) {
  const int* src = blockIdx.y ? src2 : src1;
  const int* dst = blockIdx.y ? dst2 : dst1;
  int* cursor = blockIdx.y ? cursor2 : cursor1;
  int* esrc = blockIdx.y ? esrc2 : esrc1;
  int i = blockIdx.x * blockDim.x + threadIdx.x;
  if (i < E) {
    int pos = atomicAdd(&cursor[dst[i]], 1);
    esrc[pos] = src[i];
  }
}

// ---------------- gather-reduce: agg[d] = sum over in-edges of feat[s]*dno[s] ----------
__global__ __launch_bounds__(256) void gather_reduce_kernel(
    const int* __restrict__ esrc1, const int* __restrict__ cursor1,
    const int* __restrict__ degi1, const float* __restrict__ dno1,
    const float* __restrict__ feat1, float* __restrict__ agg1,
    const int* __restrict__ esrc2, const int* __restrict__ cursor2,
    const int* __restrict__ degi2, const float* __restrict__ dno2,
    const float* __restrict__ feat2, float* __restrict__ agg2, int N) {
  const int* esrc = blockIdx.y ? esrc2 : esrc1;
  const int* cursor = blockIdx.y ? cursor2 : cursor1;
  const int* degi = blockIdx.y ? degi2 : degi1;
  const float* dno = blockIdx.y ? dno2 : dno1;
  const float* feat = blockIdx.y ? feat2 : feat1;
  float* agg = blockIdx.y ? agg2 : agg1;

  int node = blockIdx.x * 8 + (threadIdx.x >> 5);
  int l = threadIdx.x & 31;
  if (node >= N) return;
  int cnt = degi[node];
  int start = cursor[node] - cnt;
  float4 acc = {0.f, 0.f, 0.f, 0.f};
  for (int j0 = 0; j0 < cnt; j0 += 32) {
    int nb = cnt - j0; if (nb > 32) nb = 32;
    int myi = (l < nb) ? esrc[start + j0 + l] : 0;
    float mydn = dno[myi];
#pragma unroll 4
    for (int k = 0; k < nb; ++k) {
      int s = __shfl(myi, k, 32);
      float dn = __shfl(mydn, k, 32);
      float4 v = ((const float4*)(feat + (size_t)s * F))[l];
      acc.x = fmaf(v.x, dn, acc.x);
      acc.y = fmaf(v.y, dn, acc.y);
      acc.z = fmaf(v.z, dn, acc.z);
      acc.w = fmaf(v.w, dn, acc.w);
    }
  }
  ((float4*)(agg + (size_t)node * F))[l] = acc;
}

// ---------------- fused: h = agg@W * dni + b; L2-normalize; sigmoid; hg[gid] += h ----------
__global__ __launch_bounds__(256) void gemm_epi_kernel(
    const float* __restrict__ agg1, const float* __restrict__ dni1,
    const int* __restrict__ gid1, float* __restrict__ hg1,
    const float* __restrict__ agg2, const float* __restrict__ dni2,
    const int* __restrict__ gid2, float* __restrict__ hg2,
    const float* __restrict__ Wg, const float* __restrict__ bg, int N) {
  const float* agg = blockIdx.y ? agg2 : agg1;
  const float* dni = blockIdx.y ? dni2 : dni1;
  const int* gid = blockIdx.y ? gid2 : gid1;
  float* hg = blockIdx.y ? hg2 : hg1;

  __shared__ float Wl[F * F];
  __shared__ float Al[TM * F];
  __shared__ float hred[4][F];
  int tid = threadIdx.x;

  const float4* Wv = (const float4*)Wg;
  float4* Wlv = (float4*)Wl;
#pragma unroll
  for (int i = 0; i < (F * F / 4) / 256; ++i)
    Wlv[tid + i * 256] = Wv[tid + i * 256];

  int r0 = blockIdx.x * TM;
  const float4* Av = (const float4*)(agg + (size_t)r0 * F);
  float4* Alv = (float4*)Al;
#pragma unroll
  for (int i = 0; i < (TM * F / 4) / 256; ++i)
    Alv[tid + i * 256] = Av[tid + i * 256];
  __syncthreads();

  int rg = tid >> 5;   // 0..7  (4 rows each)
  int cg = tid & 31;   // 0..31 (4 cols each)

  float acc[4][4];
#pragma unroll
  for (int i = 0; i < 4; ++i)
#pragma unroll
    for (int j = 0; j < 4; ++j) acc[i][j] = 0.0f;

  for (int k0 = 0; k0 < F; k0 += 4) {
    float4 a4[4];
#pragma unroll
    for (int i = 0; i < 4; ++i)
      a4[i] = *(const float4*)&Al[(rg * 4 + i) * F + k0];
#pragma unroll
    for (int kk = 0; kk < 4; ++kk) {
      float4 wv = *(const float4*)&Wl[(k0 + kk) * F + cg * 4];
#pragma unroll
      for (int i = 0; i < 4; ++i) {
        float av = ((const float*)&a4[i])[kk];
        acc[i][0] += av * wv.x;
        acc[i][1] += av * wv.y;
        acc[i][2] += av * wv.z;
        acc[i][3] += av * wv.w;
      }
    }
  }

  float dnr[4];
  int gg[4];
#pragma unroll
  for (int i = 0; i < 4; ++i) {
    int r = r0 + rg * 4 + i;
    dnr[i] = dni[r];
    gg[i] = gid[r];
  }
  float4 bb = *(const float4*)(bg + cg * 4);
  const float* bbf = (const float*)&bb;

  float y[4][4], ssq[4];
#pragma unroll
  for (int i = 0; i < 4; ++i) {
    ssq[i] = 0.0f;
#pragma unroll
    for (int j = 0; j < 4; ++j) {
      float t = acc[i][j] * dnr[i] + bbf[j];
      y[i][j] = t;
      ssq[i] += t * t;
    }
  }
#pragma unroll
  for (int m = 1; m < 32; m <<= 1) {
#pragma unroll
    for (int i = 0; i < 4; ++i) ssq[i] += __shfl_xor(ssq[i], m);
  }

  float u[4][4];
#pragma unroll
  for (int i = 0; i < 4; ++i) {
    float inv = 1.0f / fmaxf(sqrtf(ssq[i]), 1e-12f);
#pragma unroll
    for (int j = 0; j < 4; ++j)
      u[i][j] = 1.0f / (1.0f + expf(-y[i][j] * inv));  // relu(sigmoid(x)) == sigmoid(x)
  }

  int lane = tid & 63;
  int wv_id = tid >> 6;
  int g_first = gid[r0];
  int g_last = gid[r0 + TM - 1];
  if (g_first == g_last) {
    // whole block one graph: LDS-reduce across 4 waves, 128 atomics/block
    float cs[4];
#pragma unroll
    for (int j = 0; j < 4; ++j) {
      cs[j] = u[0][j] + u[1][j] + u[2][j] + u[3][j];
      cs[j] += __shfl_xor(cs[j], 32);
    }
    if (lane < 32) {
#pragma unroll
      for (int j = 0; j < 4; ++j) hred[wv_id][cg * 4 + j] = cs[j];
    }
    __syncthreads();
    if (tid < F) {
      float s = hred[0][tid] + hred[1][tid] + hred[2][tid] + hred[3][tid];
      atomicAddF(&hg[(size_t)g_first * F + tid], s);
    }
  } else {
    int g0 = gid[r0 + wv_id * 8];
    bool ok = (gg[0] == g0) && (gg[1] == g0) && (gg[2] == g0) && (gg[3] == g0);
    if (__all(ok)) {
      float cs[4];
#pragma unroll
      for (int j = 0; j < 4; ++j) {
        cs[j] = u[0][j] + u[1][j] + u[2][j] + u[3][j];
        cs[j] += __shfl_xor(cs[j], 32);
      }
      if (lane < 32) {
#pragma unroll
        for (int j = 0; j < 4; ++j)
          atomicAddF(&hg[(size_t)g0 * F + cg * 4 + j], cs[j]);
      }
    } else {
#pragma unroll
      for (int i = 0; i < 4; ++i)
#pragma unroll
        for (int j = 0; j < 4; ++j)
          atomicAddF(&hg[(size_t)gg[i] * F + cg * 4 + j], u[i][j]);
    }
  }
}

// ---------------- final ----------------
__global__ __launch_bounds__(64) void final_kernel(
    const float* __restrict__ hg1, const int* __restrict__ cnt1,
    const float* __restrict__ hg2, const int* __restrict__ cnt2,
    const float* __restrict__ Wc, const float* __restrict__ bc,
    float* __restrict__ out) {
  __shared__ float v1[F], v2[F];
  int g = blockIdx.x, c = threadIdx.x;
  float ic1 = 1.0f / fmaxf((float)cnt1[g], 1.0f);
  float ic2 = 1.0f / fmaxf((float)cnt2[g], 1.0f);
  for (int i = c; i < F; i += 64) {
    v1[i] = hg1[(size_t)g * F + i] * ic1;
    v2[i] = hg2[(size_t)g * F + i] * ic2;
  }
  __syncthreads();
  float z1 = bc[c], z2 = bc[c];
  for (int k = 0; k < F; ++k) {
    float w = Wc[k * C + c];
    z1 += v1[k] * w;
    z2 += v2[k] * w;
  }
  float d = z1 - z2 + 1e-6f;
  d *= d;
#pragma unroll
  for (int m = 1; m < 64; m <<= 1) d += __shfl_xor(d, m);
  if (c == 0) out[g] = sqrtf(d);
}

extern "C" void kernel_launch(void* const* d_in, const int* in_sizes, int n_in,
                              void* d_out, int out_size, void* d_ws, size_t ws_size,
                              hipStream_t stream) {
  const float* feat1 = (const float*)d_in[0];
  const float* feat2 = (const float*)d_in[1];
  const int* src1 = (const int*)d_in[2];
  const int* dst1 = (const int*)d_in[3];
  const int* gid1 = (const int*)d_in[4];
  const int* src2 = (const int*)d_in[5];
  const int* dst2 = (const int*)d_in[6];
  const int* gid2 = (const int*)d_in[7];
  const float* Wg = (const float*)d_in[8];
  const float* bg = (const float*)d_in[9];
  const float* Wc = (const float*)d_in[10];
  const float* bc = (const float*)d_in[11];
  float* out = (float*)d_out;

  int N = in_sizes[0] / F;
  int E = in_sizes[2];
  int NB = (N + SCHUNK - 1) / SCHUNK;   // 98 for N=100000

  // ---- workspace layout: zero-init region first ----
  char* w = (char*)d_ws;
  int* dego1 = (int*)w; w += (size_t)N * 4;
  int* degi1 = (int*)w; w += (size_t)N * 4;
  int* dego2 = (int*)w; w += (size_t)N * 4;
  int* degi2 = (int*)w; w += (size_t)N * 4;
  float* hg1 = (float*)w; w += (size_t)G * F * 4;
  float* hg2 = (float*)w; w += (size_t)G * F * 4;
  size_t zbytes = (size_t)(w - (char*)d_ws);
  // non-zeroed scratch:
  int* cnt1 = (int*)w; w += G * 4;
  int* cnt2 = (int*)w; w += G * 4;
  float* agg1 = (float*)w; w += (size_t)N * F * 4;
  float* agg2 = (float*)w; w += (size_t)N * F * 4;
  float* dno1 = (float*)w; w += (size_t)N * 4;
  float* dni1 = (float*)w; w += (size_t)N * 4;
  float* dno2 = (float*)w; w += (size_t)N * 4;
  float* dni2 = (float*)w; w += (size_t)N * 4;
  int* cursor1 = (int*)w; w += (size_t)N * 4;
  int* cursor2 = (int*)w; w += (size_t)N * 4;
  int* esrc1 = (int*)w; w += (size_t)E * 4;
  int* esrc2 = (int*)w; w += (size_t)E * 4;
  int* bsum1 = (int*)w; w += 256 * 4;
  int* bsum2 = (int*)w; w += 256 * 4;
  if ((size_t)(w - (char*)d_ws) > ws_size) return;  // fail loudly (output stays poisoned)

  hipMemsetAsync(d_ws, 0, zbytes, stream);

  int eb = (E + 255) / 256;
  deg_kernel<<<dim3(eb, 2), 256, 0, stream>>>(src1, dst1, src2, dst2,
                                              dego1, degi1, dego2, degi2, E);

  int nb = (N + 255) / 256;
  dnorm_kernel<<<dim3(nb, 2), 256, 0, stream>>>(dego1, degi1, dego2, degi2,
                                                dno1, dni1, dno2, dni2, N);
  cnt_kernel<<<2, 128, 0, stream>>>(gid1, gid2, cnt1, cnt2, N);

  scanA_kernel<<<NB, 256, 0, stream>>>(degi1, bsum1, N);
  scanA_kernel<<<NB, 256, 0, stream>>>(degi2, bsum2, N);
  scanB_kernel<<<1, 256, 0, stream>>>(bsum1, NB);
  scanB_kernel<<<1, 256, 0, stream>>>(bsum2, NB);
  scanC_kernel<<<NB, 256, 0, stream>>>(degi1, bsum1, cursor1, N);
  scanC_kernel<<<NB, 256, 0, stream>>>(degi2, bsum2, cursor2, N);

  scatter_kernel<<<dim3(eb, 2), 256, 0, stream>>>(src1, dst1, src2, dst2,
                                                  cursor1, cursor2, esrc1, esrc2, E);

  int gbr = (N + 7) / 8;
  gather_reduce_kernel<<<dim3(gbr, 2), 256, 0, stream>>>(
      esrc1, cursor1, degi1, dno1, feat1, agg1,
      esrc2, cursor2, degi2, dno2, feat2, agg2, N);

  int gb = N / TM;
  gemm_epi_kernel<<<dim3(gb, 2), 256, 0, stream>>>(
      agg1, dni1, gid1, hg1, agg2, dni2, gid2, hg2, Wg, bg, N);

  final_kernel<<<G, 64, 0, stream>>>(hg1, cnt1, hg2, cnt2, Wc, bc, out);
}

// Round 4
// 795.033 us; speedup vs baseline: 8.1893x; 1.3659x over previous
//
#include <hip/hip_runtime.h>
#include <math.h>

// Problem constants: F=IN_FEATS=H2=128, C=N_CLASSES=64, G=N_GRAPHS=128
#define F 128
#define C 64
#define G 128
#define TM 32        // rows per block in gemm_epi_kernel; N (100000) % 32 == 0
#define KMAX 512     // max coarse buckets (N <= 131072)
#define P1CH 8192    // edges per block in pass1
#define BHCH 16384   // edges per block in bhist
#define CAP 16384    // max edges per coarse bucket staged in LDS (mean ~4092)

__device__ __forceinline__ void atomicAddF(float* p, float v) {
  __hip_atomic_fetch_add(p, v, __ATOMIC_RELAXED, __HIP_MEMORY_SCOPE_AGENT);
}

// ---------------- src-side degree counting (direct atomics) ----------------
__global__ void deg_kernel(const int* __restrict__ src1, const int* __restrict__ src2,
                           int* __restrict__ dego1, int* __restrict__ dego2, int E) {
  const int* src = blockIdx.y ? src2 : src1;
  int* dego = blockIdx.y ? dego2 : dego1;
  int i = blockIdx.x * blockDim.x + threadIdx.x;
  if (i < E) atomicAdd(&dego[src[i]], 1);
}

// ---------------- dno = deg_out^-1/2 ----------------
__global__ void dnorm_kernel(const int* __restrict__ dego1, const int* __restrict__ dego2,
                             float* __restrict__ dno1, float* __restrict__ dno2, int N) {
  const int* dego = blockIdx.y ? dego2 : dego1;
  float* dno = blockIdx.y ? dno2 : dno1;
  int i = blockIdx.x * blockDim.x + threadIdx.x;
  if (i < N) {
    int a = dego[i]; if (a < 1) a = 1;
    dno[i] = 1.0f / sqrtf((float)a);
  }
}

// ---------------- per-graph node counts via binary search (gid sorted) ----------------
__global__ __launch_bounds__(128) void cnt_kernel(const int* __restrict__ gid1,
                                                  const int* __restrict__ gid2,
                                                  int* __restrict__ cnt1,
                                                  int* __restrict__ cnt2, int N) {
  const int* gid = blockIdx.x ? gid2 : gid1;
  int* cnt = blockIdx.x ? cnt2 : cnt1;
  int g = threadIdx.x;
  int lo = 0, hi = N;
  while (lo < hi) { int m = (lo + hi) >> 1; if (gid[m] < g) lo = m + 1; else hi = m; }
  int lo2 = lo, hi2 = N;
  while (lo2 < hi2) { int m = (lo2 + hi2) >> 1; if (gid[m] <= g) lo2 = m + 1; else hi2 = m; }
  cnt[g] = lo2 - lo;
}

// ---------------- coarse histogram of dst>>8 (LDS-privatized) ----------------
__global__ __launch_bounds__(256) void bhist_kernel(const int* __restrict__ dst1,
                                                    const int* __restrict__ dst2,
                                                    int* __restrict__ bcnt1,
                                                    int* __restrict__ bcnt2, int E, int K) {
  const int* dst = blockIdx.y ? dst2 : dst1;
  int* bcnt = blockIdx.y ? bcnt2 : bcnt1;
  __shared__ int c[KMAX];
  int t = threadIdx.x;
  for (int k = t; k < K; k += 256) c[k] = 0;
  __syncthreads();
  int e0 = blockIdx.x * BHCH;
  int e1 = e0 + BHCH; if (e1 > E) e1 = E;
  for (int i = e0 + t; i < e1; i += 256) atomicAdd(&c[dst[i] >> 8], 1);
  __syncthreads();
  for (int k = t; k < K; k += 256)
    if (c[k]) atomicAdd(&bcnt[k], c[k]);
}

// ---------------- exclusive scan over K coarse buckets (1 block/branch) ----------------
__global__ __launch_bounds__(512) void bscan_kernel(const int* __restrict__ bcnt1,
                                                    const int* __restrict__ bcnt2,
                                                    int* __restrict__ bstart1,
                                                    int* __restrict__ bstart2,
                                                    int* __restrict__ bcur1,
                                                    int* __restrict__ bcur2, int K, int E) {
  const int* bcnt = blockIdx.x ? bcnt2 : bcnt1;
  int* bstart = blockIdx.x ? bstart2 : bstart1;
  int* bcur = blockIdx.x ? bcur2 : bcur1;
  __shared__ int s[512];
  int t = threadIdx.x;
  int v = (t < K) ? bcnt[t] : 0;
  s[t] = v;
  __syncthreads();
  for (int off = 1; off < 512; off <<= 1) {
    int x = (t >= off) ? s[t - off] : 0;
    __syncthreads();
    s[t] += x;
    __syncthreads();
  }
  int excl = s[t] - v;
  if (t < K) { bstart[t] = excl; bcur[t] = excl; }
  if (t == 0) bstart[K] = E;
}

// ---------------- pass1: bin edges into coarse buckets, packed (dst&255)<<24 | src ----------
__global__ __launch_bounds__(256) void pass1_kernel(
    const int* __restrict__ src1, const int* __restrict__ dst1,
    const int* __restrict__ src2, const int* __restrict__ dst2,
    int* __restrict__ bcur1, int* __restrict__ bcur2,
    unsigned* __restrict__ epk1, unsigned* __restrict__ epk2, int E, int K) {
  const int* src = blockIdx.y ? src2 : src1;
  const int* dst = blockIdx.y ? dst2 : dst1;
  int* bcur = blockIdx.y ? bcur2 : bcur1;
  unsigned* epk = blockIdx.y ? epk2 : epk1;

  __shared__ int cnt[KMAX], base[KMAX], cnt2[KMAX];
  int t = threadIdx.x;
  for (int k = t; k < K; k += 256) { cnt[k] = 0; cnt2[k] = 0; }
  __syncthreads();
  int e0 = blockIdx.x * P1CH;
  int e1 = e0 + P1CH; if (e1 > E) e1 = E;
  for (int i = e0 + t; i < e1; i += 256)
    atomicAdd(&cnt[dst[i] >> 8], 1);
  __syncthreads();
  for (int k = t; k < K; k += 256) {
    int c = cnt[k];
    if (c) base[k] = atomicAdd(&bcur[k], c);
  }
  __syncthreads();
  for (int i = e0 + t; i < e1; i += 256) {
    int d = dst[i];
    int k = d >> 8;
    int r = atomicAdd(&cnt2[k], 1);
    epk[base[k] + r] = ((unsigned)(d & 255) << 24) | (unsigned)src[i];
  }
}

// ---------------- pass2: bucket-local fine sort; emits degi/dni/cursor + esrc in-place ------
__global__ __launch_bounds__(256) void pass2_kernel(
    const int* __restrict__ bstart1, const int* __restrict__ bstart2,
    unsigned* __restrict__ epk1, unsigned* __restrict__ epk2,
    int* __restrict__ degi1, int* __restrict__ degi2,
    float* __restrict__ dni1, float* __restrict__ dni2,
    int* __restrict__ cursor1, int* __restrict__ cursor2, int N) {
  const int* bstart = blockIdx.y ? bstart2 : bstart1;
  unsigned* epk = blockIdx.y ? epk2 : epk1;   // also the esrc output (in-place)
  int* degi = blockIdx.y ? degi2 : degi1;
  float* dni = blockIdx.y ? dni2 : dni1;
  int* cursor = blockIdx.y ? cursor2 : cursor1;

  __shared__ unsigned pk[CAP];
  __shared__ int lcnt[256];
  __shared__ int lcur[256];   // scan buffer, then atomic cursors

  int b = blockIdx.x;
  int t = threadIdx.x;
  int s0 = bstart[b], s1 = bstart[b + 1];
  int M = s1 - s0;            // <= CAP for uniform-random dst (mean ~4092, sigma ~64)

  lcnt[t] = 0;
  for (int e = t; e < M; e += 256) pk[e] = epk[s0 + e];
  __syncthreads();
  for (int e = t; e < M; e += 256) atomicAdd(&lcnt[pk[e] >> 24], 1);
  __syncthreads();

  int v = lcnt[t];
  lcur[t] = v;
  __syncthreads();
  for (int off = 1; off < 256; off <<= 1) {
    int x = (t >= off) ? lcur[t - off] : 0;
    __syncthreads();
    lcur[t] += x;
    __syncthreads();
  }
  int excl = lcur[t] - v;
  int startp = s0 + excl;
  int node = (b << 8) + t;
  if (node < N) {
    degi[node] = v;
    int vc = v < 1 ? 1 : v;
    dni[node] = 1.0f / sqrtf((float)vc);
    cursor[node] = startp;
  }
  __syncthreads();
  lcur[t] = startp;
  __syncthreads();
  for (int e = t; e < M; e += 256) {
    unsigned p = pk[e];
    int dl = p >> 24;
    int pos = atomicAdd(&lcur[dl], 1);
    epk[pos] = p & 0xFFFFFFu;   // esrc value (node id < 2^17)
  }
}

// ---------------- gather-reduce: agg[d] = sum over in-edges of feat[s]*dno[s] ----------
__global__ __launch_bounds__(256) void gather_reduce_kernel(
    const int* __restrict__ esrc1, const int* __restrict__ cursor1,
    const int* __restrict__ degi1, const float* __restrict__ dno1,
    const float* __restrict__ feat1, float* __restrict__ agg1,
    const int* __restrict__ esrc2, const int* __restrict__ cursor2,
    const int* __restrict__ degi2, const float* __restrict__ dno2,
    const float* __restrict__ feat2, float* __restrict__ agg2, int N) {
  const int* esrc = blockIdx.y ? esrc2 : esrc1;
  const int* cursor = blockIdx.y ? cursor2 : cursor1;
  const int* degi = blockIdx.y ? degi2 : degi1;
  const float* dno = blockIdx.y ? dno2 : dno1;
  const float* feat = blockIdx.y ? feat2 : feat1;
  float* agg = blockIdx.y ? agg2 : agg1;

  int node = blockIdx.x * 8 + (threadIdx.x >> 5);
  int l = threadIdx.x & 31;
  if (node >= N) return;
  int cnt = degi[node];
  int start = cursor[node];
  float4 acc = {0.f, 0.f, 0.f, 0.f};
  for (int j0 = 0; j0 < cnt; j0 += 32) {
    int nb = cnt - j0; if (nb > 32) nb = 32;
    int myi = (l < nb) ? esrc[start + j0 + l] : 0;
    float mydn = dno[myi];
#pragma unroll 4
    for (int k = 0; k < nb; ++k) {
      int s = __shfl(myi, k, 32);
      float dn = __shfl(mydn, k, 32);
      float4 v = ((const float4*)(feat + (size_t)s * F))[l];
      acc.x = fmaf(v.x, dn, acc.x);
      acc.y = fmaf(v.y, dn, acc.y);
      acc.z = fmaf(v.z, dn, acc.z);
      acc.w = fmaf(v.w, dn, acc.w);
    }
  }
  ((float4*)(agg + (size_t)node * F))[l] = acc;
}

// ---------------- fused: h = agg@W * dni + b; L2-normalize; sigmoid; hg[gid] += h ----------
__global__ __launch_bounds__(256) void gemm_epi_kernel(
    const float* __restrict__ agg1, const float* __restrict__ dni1,
    const int* __restrict__ gid1, float* __restrict__ hg1,
    const float* __restrict__ agg2, const float* __restrict__ dni2,
    const int* __restrict__ gid2, float* __restrict__ hg2,
    const float* __restrict__ Wg, const float* __restrict__ bg, int N) {
  const float* agg = blockIdx.y ? agg2 : agg1;
  const float* dni = blockIdx.y ? dni2 : dni1;
  const int* gid = blockIdx.y ? gid2 : gid1;
  float* hg = blockIdx.y ? hg2 : hg1;

  __shared__ float Wl[F * F];
  __shared__ float Al[TM * F];
  __shared__ float hred[4][F];
  int tid = threadIdx.x;

  const float4* Wv = (const float4*)Wg;
  float4* Wlv = (float4*)Wl;
#pragma unroll
  for (int i = 0; i < (F * F / 4) / 256; ++i)
    Wlv[tid + i * 256] = Wv[tid + i * 256];

  int r0 = blockIdx.x * TM;
  const float4* Av = (const float4*)(agg + (size_t)r0 * F);
  float4* Alv = (float4*)Al;
#pragma unroll
  for (int i = 0; i < (TM * F / 4) / 256; ++i)
    Alv[tid + i * 256] = Av[tid + i * 256];
  __syncthreads();

  int rg = tid >> 5;   // 0..7  (4 rows each)
  int cg = tid & 31;   // 0..31 (4 cols each)

  float acc[4][4];
#pragma unroll
  for (int i = 0; i < 4; ++i)
#pragma unroll
    for (int j = 0; j < 4; ++j) acc[i][j] = 0.0f;

  for (int k0 = 0; k0 < F; k0 += 4) {
    float4 a4[4];
#pragma unroll
    for (int i = 0; i < 4; ++i)
      a4[i] = *(const float4*)&Al[(rg * 4 + i) * F + k0];
#pragma unroll
    for (int kk = 0; kk < 4; ++kk) {
      float4 wv = *(const float4*)&Wl[(k0 + kk) * F + cg * 4];
#pragma unroll
      for (int i = 0; i < 4; ++i) {
        float av = ((const float*)&a4[i])[kk];
        acc[i][0] += av * wv.x;
        acc[i][1] += av * wv.y;
        acc[i][2] += av * wv.z;
        acc[i][3] += av * wv.w;
      }
    }
  }

  float dnr[4];
  int gg[4];
#pragma unroll
  for (int i = 0; i < 4; ++i) {
    int r = r0 + rg * 4 + i;
    dnr[i] = dni[r];
    gg[i] = gid[r];
  }
  float4 bb = *(const float4*)(bg + cg * 4);
  const float* bbf = (const float*)&bb;

  float y[4][4], ssq[4];
#pragma unroll
  for (int i = 0; i < 4; ++i) {
    ssq[i] = 0.0f;
#pragma unroll
    for (int j = 0; j < 4; ++j) {
      float t = acc[i][j] * dnr[i] + bbf[j];
      y[i][j] = t;
      ssq[i] += t * t;
    }
  }
#pragma unroll
  for (int m = 1; m < 32; m <<= 1) {
#pragma unroll
    for (int i = 0; i < 4; ++i) ssq[i] += __shfl_xor(ssq[i], m);
  }

  float u[4][4];
#pragma unroll
  for (int i = 0; i < 4; ++i) {
    float inv = 1.0f / fmaxf(sqrtf(ssq[i]), 1e-12f);
#pragma unroll
    for (int j = 0; j < 4; ++j)
      u[i][j] = 1.0f / (1.0f + expf(-y[i][j] * inv));  // relu(sigmoid(x)) == sigmoid(x)
  }

  int lane = tid & 63;
  int wv_id = tid >> 6;
  int g_first = gid[r0];
  int g_last = gid[r0 + TM - 1];
  if (g_first == g_last) {
    float cs[4];
#pragma unroll
    for (int j = 0; j < 4; ++j) {
      cs[j] = u[0][j] + u[1][j] + u[2][j] + u[3][j];
      cs[j] += __shfl_xor(cs[j], 32);
    }
    if (lane < 32) {
#pragma unroll
      for (int j = 0; j < 4; ++j) hred[wv_id][cg * 4 + j] = cs[j];
    }
    __syncthreads();
    if (tid < F) {
      float s = hred[0][tid] + hred[1][tid] + hred[2][tid] + hred[3][tid];
      atomicAddF(&hg[(size_t)g_first * F + tid], s);
    }
  } else {
    int g0 = gid[r0 + wv_id * 8];
    bool ok = (gg[0] == g0) && (gg[1] == g0) && (gg[2] == g0) && (gg[3] == g0);
    if (__all(ok)) {
      float cs[4];
#pragma unroll
      for (int j = 0; j < 4; ++j) {
        cs[j] = u[0][j] + u[1][j] + u[2][j] + u[3][j];
        cs[j] += __shfl_xor(cs[j], 32);
      }
      if (lane < 32) {
#pragma unroll
        for (int j = 0; j < 4; ++j)
          atomicAddF(&hg[(size_t)g0 * F + cg * 4 + j], cs[j]);
      }
    } else {
#pragma unroll
      for (int i = 0; i < 4; ++i)
#pragma unroll
        for (int j = 0; j < 4; ++j)
          atomicAddF(&hg[(size_t)gg[i] * F + cg * 4 + j], u[i][j]);
    }
  }
}

// ---------------- final ----------------
__global__ __launch_bounds__(64) void final_kernel(
    const float* __restrict__ hg1, const int* __restrict__ cnt1,
    const float* __restrict__ hg2, const int* __restrict__ cnt2,
    const float* __restrict__ Wc, const float* __restrict__ bc,
    float* __restrict__ out) {
  __shared__ float v1[F], v2[F];
  int g = blockIdx.x, c = threadIdx.x;
  float ic1 = 1.0f / fmaxf((float)cnt1[g], 1.0f);
  float ic2 = 1.0f / fmaxf((float)cnt2[g], 1.0f);
  for (int i = c; i < F; i += 64) {
    v1[i] = hg1[(size_t)g * F + i] * ic1;
    v2[i] = hg2[(size_t)g * F + i] * ic2;
  }
  __syncthreads();
  float z1 = bc[c], z2 = bc[c];
  for (int k = 0; k < F; ++k) {
    float w = Wc[k * C + c];
    z1 += v1[k] * w;
    z2 += v2[k] * w;
  }
  float d = z1 - z2 + 1e-6f;
  d *= d;
#pragma unroll
  for (int m = 1; m < 64; m <<= 1) d += __shfl_xor(d, m);
  if (c == 0) out[g] = sqrtf(d);
}

extern "C" void kernel_launch(void* const* d_in, const int* in_sizes, int n_in,
                              void* d_out, int out_size, void* d_ws, size_t ws_size,
                              hipStream_t stream) {
  const float* feat1 = (const float*)d_in[0];
  const float* feat2 = (const float*)d_in[1];
  const int* src1 = (const int*)d_in[2];
  const int* dst1 = (const int*)d_in[3];
  const int* gid1 = (const int*)d_in[4];
  const int* src2 = (const int*)d_in[5];
  const int* dst2 = (const int*)d_in[6];
  const int* gid2 = (const int*)d_in[7];
  const float* Wg = (const float*)d_in[8];
  const float* bg = (const float*)d_in[9];
  const float* Wc = (const float*)d_in[10];
  const float* bc = (const float*)d_in[11];
  float* out = (float*)d_out;

  int N = in_sizes[0] / F;
  int E = in_sizes[2];
  int K = (N + 255) >> 8;           // coarse buckets (391 for N=100000)
  if (K > KMAX) return;             // unsupported size: fail loudly

  // ---- workspace layout: zero-init region first (all sizes multiples of 16B) ----
  char* w = (char*)d_ws;
  int* dego1 = (int*)w; w += (size_t)N * 4;
  int* dego2 = (int*)w; w += (size_t)N * 4;
  float* hg1 = (float*)w; w += (size_t)G * F * 4;
  float* hg2 = (float*)w; w += (size_t)G * F * 4;
  int* bcnt1 = (int*)w; w += KMAX * 4;
  int* bcnt2 = (int*)w; w += KMAX * 4;
  size_t zbytes = (size_t)(w - (char*)d_ws);
  // non-zeroed scratch:
  float* agg1 = (float*)w; w += (size_t)N * F * 4;
  float* agg2 = (float*)w; w += (size_t)N * F * 4;
  unsigned* epk1 = (unsigned*)w; w += (size_t)E * 4;   // pass1 packed; pass2 rewrites as esrc
  unsigned* epk2 = (unsigned*)w; w += (size_t)E * 4;
  int* degi1 = (int*)w; w += (size_t)N * 4;
  int* degi2 = (int*)w; w += (size_t)N * 4;
  float* dno1 = (float*)w; w += (size_t)N * 4;
  float* dno2 = (float*)w; w += (size_t)N * 4;
  float* dni1 = (float*)w; w += (size_t)N * 4;
  float* dni2 = (float*)w; w += (size_t)N * 4;
  int* cursor1 = (int*)w; w += (size_t)N * 4;
  int* cursor2 = (int*)w; w += (size_t)N * 4;
  int* cnt1 = (int*)w; w += 128 * 4;
  int* cnt2 = (int*)w; w += 128 * 4;
  int* bstart1 = (int*)w; w += (KMAX + 4) * 4;
  int* bstart2 = (int*)w; w += (KMAX + 4) * 4;
  int* bcur1 = (int*)w; w += KMAX * 4;
  int* bcur2 = (int*)w; w += KMAX * 4;
  if ((size_t)(w - (char*)d_ws) > ws_size) return;  // fail loudly (output stays poisoned)

  hipMemsetAsync(d_ws, 0, zbytes, stream);

  int eb = (E + 255) / 256;
  deg_kernel<<<dim3(eb, 2), 256, 0, stream>>>(src1, src2, dego1, dego2, E);

  int bhb = (E + BHCH - 1) / BHCH;
  bhist_kernel<<<dim3(bhb, 2), 256, 0, stream>>>(dst1, dst2, bcnt1, bcnt2, E, K);
  bscan_kernel<<<2, 512, 0, stream>>>(bcnt1, bcnt2, bstart1, bstart2, bcur1, bcur2, K, E);

  int nb = (N + 255) / 256;
  dnorm_kernel<<<dim3(nb, 2), 256, 0, stream>>>(dego1, dego2, dno1, dno2, N);
  cnt_kernel<<<2, 128, 0, stream>>>(gid1, gid2, cnt1, cnt2, N);

  int p1b = (E + P1CH - 1) / P1CH;
  pass1_kernel<<<dim3(p1b, 2), 256, 0, stream>>>(src1, dst1, src2, dst2,
                                                 bcur1, bcur2, epk1, epk2, E, K);
  pass2_kernel<<<dim3(K, 2), 256, 0, stream>>>(bstart1, bstart2, epk1, epk2,
                                               degi1, degi2, dni1, dni2,
                                               cursor1, cursor2, N);

  int gbr = (N + 7) / 8;
  gather_reduce_kernel<<<dim3(gbr, 2), 256, 0, stream>>>(
      (const int*)epk1, cursor1, degi1, dno1, feat1, agg1,
      (const int*)epk2, cursor2, degi2, dno2, feat2, agg2, N);

  int gb = N / TM;
  gemm_epi_kernel<<<dim3(gb, 2), 256, 0, stream>>>(
      agg1, dni1, gid1, hg1, agg2, dni2, gid2, hg2, Wg, bg, N);

  final_kernel<<<G, 64, 0, stream>>>(hg1, cnt1, hg2, cnt2, Wc, bc, out);
}

// Round 6
// 733.671 us; speedup vs baseline: 8.8743x; 1.0836x over previous
//
#include <hip/hip_runtime.h>
#include <hip/hip_fp16.h>
#include <math.h>

// Problem constants: F=IN_FEATS=H2=128, C=N_CLASSES=64, G=N_GRAPHS=128
#define F 128
#define C 64
#define G 128
#define TM 32        // rows per block in gemm_epi_kernel; N (100000) % 32 == 0
#define KMAX 512     // max coarse buckets (N <= 131072)
#define P1CH 8192    // edges per block in pass1
#define BHCH 16384   // edges per block in bhist
#define CAP 16384    // max edges per coarse bucket staged in LDS (mean ~4092)

__device__ __forceinline__ void atomicAddF(float* p, float v) {
  __hip_atomic_fetch_add(p, v, __ATOMIC_RELAXED, __HIP_MEMORY_SCOPE_AGENT);
}

// ---------------- src-side degree counting (direct atomics) ----------------
__global__ void deg_kernel(const int* __restrict__ src1, const int* __restrict__ src2,
                           int* __restrict__ dego1, int* __restrict__ dego2, int E) {
  const int* src = blockIdx.y ? src2 : src1;
  int* dego = blockIdx.y ? dego2 : dego1;
  int i = blockIdx.x * blockDim.x + threadIdx.x;
  if (i < E) atomicAdd(&dego[src[i]], 1);
}

// ---------------- featsc[n][j] = fp16(feat[n][j] * dego[n]^-1/2) ----------------
__global__ __launch_bounds__(256) void fscale_kernel(
    const float* __restrict__ feat1, const float* __restrict__ feat2,
    const int* __restrict__ dego1, const int* __restrict__ dego2,
    __half* __restrict__ fs1, __half* __restrict__ fs2, int N) {
  const float* feat = blockIdx.y ? feat2 : feat1;
  const int* dego = blockIdx.y ? dego2 : dego1;
  __half* fs = blockIdx.y ? fs2 : fs1;
  int i = blockIdx.x * blockDim.x + threadIdx.x;    // over N*F/4
  if (i >= N * (F / 4)) return;
  int node = i >> 5;                                 // F/4 == 32
  int a = dego[node]; if (a < 1) a = 1;
  float dn = 1.0f / sqrtf((float)a);
  float4 v = ((const float4*)feat)[i];
  unsigned short h0 = __half_as_ushort(__float2half(v.x * dn));
  unsigned short h1 = __half_as_ushort(__float2half(v.y * dn));
  unsigned short h2 = __half_as_ushort(__float2half(v.z * dn));
  unsigned short h3 = __half_as_ushort(__float2half(v.w * dn));
  unsigned long long pk = (unsigned long long)h0 | ((unsigned long long)h1 << 16) |
                          ((unsigned long long)h2 << 32) | ((unsigned long long)h3 << 48);
  ((unsigned long long*)fs)[i] = pk;
}

// ---------------- per-graph node counts via binary search (gid sorted) ----------------
__global__ __launch_bounds__(128) void cnt_kernel(const int* __restrict__ gid1,
                                                  const int* __restrict__ gid2,
                                                  int* __restrict__ cnt1,
                                                  int* __restrict__ cnt2, int N) {
  const int* gid = blockIdx.x ? gid2 : gid1;
  int* cnt = blockIdx.x ? cnt2 : cnt1;
  int g = threadIdx.x;
  int lo = 0, hi = N;
  while (lo < hi) { int m = (lo + hi) >> 1; if (gid[m] < g) lo = m + 1; else hi = m; }
  int lo2 = lo, hi2 = N;
  while (lo2 < hi2) { int m = (lo2 + hi2) >> 1; if (gid[m] <= g) lo2 = m + 1; else hi2 = m; }
  cnt[g] = lo2 - lo;
}

// ---------------- coarse histogram of dst>>8 (LDS-privatized) ----------------
__global__ __launch_bounds__(256) void bhist_kernel(const int* __restrict__ dst1,
                                                    const int* __restrict__ dst2,
                                                    int* __restrict__ bcnt1,
                                                    int* __restrict__ bcnt2, int E, int K) {
  const int* dst = blockIdx.y ? dst2 : dst1;
  int* bcnt = blockIdx.y ? bcnt2 : bcnt1;
  __shared__ int c[KMAX];
  int t = threadIdx.x;
  for (int k = t; k < K; k += 256) c[k] = 0;
  __syncthreads();
  int e0 = blockIdx.x * BHCH;
  int e1 = e0 + BHCH; if (e1 > E) e1 = E;
  for (int i = e0 + t; i < e1; i += 256) atomicAdd(&c[dst[i] >> 8], 1);
  __syncthreads();
  for (int k = t; k < K; k += 256)
    if (c[k]) atomicAdd(&bcnt[k], c[k]);
}

// ---------------- exclusive scan over K coarse buckets (1 block/branch) ----------------
__global__ __launch_bounds__(512) void bscan_kernel(const int* __restrict__ bcnt1,
                                                    const int* __restrict__ bcnt2,
                                                    int* __restrict__ bstart1,
                                                    int* __restrict__ bstart2,
                                                    int* __restrict__ bcur1,
                                                    int* __restrict__ bcur2, int K, int E) {
  const int* bcnt = blockIdx.x ? bcnt2 : bcnt1;
  int* bstart = blockIdx.x ? bstart2 : bstart1;
  int* bcur = blockIdx.x ? bcur2 : bcur1;
  __shared__ int s[512];
  int t = threadIdx.x;
  int v = (t < K) ? bcnt[t] : 0;
  s[t] = v;
  __syncthreads();
  for (int off = 1; off < 512; off <<= 1) {
    int x = (t >= off) ? s[t - off] : 0;
    __syncthreads();
    s[t] += x;
    __syncthreads();
  }
  int excl = s[t] - v;
  if (t < K) { bstart[t] = excl; bcur[t] = excl; }
  if (t == 0) bstart[K] = E;
}

// ---------------- pass1: bin edges into coarse buckets, packed (dst&255)<<24 | src ----------
__global__ __launch_bounds__(256) void pass1_kernel(
    const int* __restrict__ src1, const int* __restrict__ dst1,
    const int* __restrict__ src2, const int* __restrict__ dst2,
    int* __restrict__ bcur1, int* __restrict__ bcur2,
    unsigned* __restrict__ epk1, unsigned* __restrict__ epk2, int E, int K) {
  const int* src = blockIdx.y ? src2 : src1;
  const int* dst = blockIdx.y ? dst2 : dst1;
  int* bcur = blockIdx.y ? bcur2 : bcur1;
  unsigned* epk = blockIdx.y ? epk2 : epk1;

  __shared__ int cnt[KMAX], base[KMAX], cnt2[KMAX];
  int t = threadIdx.x;
  for (int k = t; k < K; k += 256) { cnt[k] = 0; cnt2[k] = 0; }
  __syncthreads();
  int e0 = blockIdx.x * P1CH;
  int e1 = e0 + P1CH; if (e1 > E) e1 = E;
  for (int i = e0 + t; i < e1; i += 256)
    atomicAdd(&cnt[dst[i] >> 8], 1);
  __syncthreads();
  for (int k = t; k < K; k += 256) {
    int c = cnt[k];
    if (c) base[k] = atomicAdd(&bcur[k], c);
  }
  __syncthreads();
  for (int i = e0 + t; i < e1; i += 256) {
    int d = dst[i];
    int k = d >> 8;
    int r = atomicAdd(&cnt2[k], 1);
    epk[base[k] + r] = ((unsigned)(d & 255) << 24) | (unsigned)src[i];
  }
}

// ---------------- pass2: bucket-local fine sort; emits degi/dni/cursor + esrc in-place ------
__global__ __launch_bounds__(256) void pass2_kernel(
    const int* __restrict__ bstart1, const int* __restrict__ bstart2,
    unsigned* __restrict__ epk1, unsigned* __restrict__ epk2,
    int* __restrict__ degi1, int* __restrict__ degi2,
    float* __restrict__ dni1, float* __restrict__ dni2,
    int* __restrict__ cursor1, int* __restrict__ cursor2, int N) {
  const int* bstart = blockIdx.y ? bstart2 : bstart1;
  unsigned* epk = blockIdx.y ? epk2 : epk1;   // also the esrc output (in-place)
  int* degi = blockIdx.y ? degi2 : degi1;
  float* dni = blockIdx.y ? dni2 : dni1;
  int* cursor = blockIdx.y ? cursor2 : cursor1;

  __shared__ unsigned pk[CAP];
  __shared__ int lcnt[256];
  __shared__ int lcur[256];

  int b = blockIdx.x;
  int t = threadIdx.x;
  int s0 = bstart[b], s1 = bstart[b + 1];
  int M = s1 - s0;

  lcnt[t] = 0;
  for (int e = t; e < M; e += 256) pk[e] = epk[s0 + e];
  __syncthreads();
  for (int e = t; e < M; e += 256) atomicAdd(&lcnt[pk[e] >> 24], 1);
  __syncthreads();

  int v = lcnt[t];
  lcur[t] = v;
  __syncthreads();
  for (int off = 1; off < 256; off <<= 1) {
    int x = (t >= off) ? lcur[t - off] : 0;
    __syncthreads();
    lcur[t] += x;
    __syncthreads();
  }
  int excl = lcur[t] - v;
  int startp = s0 + excl;
  int node = (b << 8) + t;
  if (node < N) {
    degi[node] = v;
    int vc = v < 1 ? 1 : v;
    dni[node] = 1.0f / sqrtf((float)vc);
    cursor[node] = startp;
  }
  __syncthreads();
  lcur[t] = startp;
  __syncthreads();
  for (int e = t; e < M; e += 256) {
    unsigned p = pk[e];
    int dl = p >> 24;
    int pos = atomicAdd(&lcur[dl], 1);
    epk[pos] = p & 0xFFFFFFu;   // esrc value (node id < 2^17)
  }
}

// ---------------- gather-reduce: agg[d] = sum over in-edges of featsc[s] (fp16 rows) -------
__global__ __launch_bounds__(256) void gather_kernel(
    const int* __restrict__ esrc, const int* __restrict__ cursor,
    const int* __restrict__ degi, const __half* __restrict__ featsc,
    __half* __restrict__ aggh, int N) {
  int node = blockIdx.x * 8 + (threadIdx.x >> 5);
  int l = threadIdx.x & 31;
  if (node >= N) return;
  int cnt = degi[node];
  int start = cursor[node];
  float4 acc = {0.f, 0.f, 0.f, 0.f};
  for (int j0 = 0; j0 < cnt; j0 += 32) {
    int nb = cnt - j0; if (nb > 32) nb = 32;
    int myi = (l < nb) ? __builtin_nontemporal_load(&esrc[start + j0 + l]) : 0;
#pragma unroll 4
    for (int k = 0; k < nb; ++k) {
      int s = __shfl(myi, k, 32);
      unsigned long long rv = ((const unsigned long long*)(featsc + (size_t)s * F))[l];
      union { unsigned long long u; __half2 h[2]; } U; U.u = rv;
      float2 f0 = __half22float2(U.h[0]);
      float2 f1 = __half22float2(U.h[1]);
      acc.x += f0.x; acc.y += f0.y; acc.z += f1.x; acc.w += f1.y;
    }
  }
  unsigned long long o =
      (unsigned long long)__half_as_ushort(__float2half(acc.x)) |
      ((unsigned long long)__half_as_ushort(__float2half(acc.y)) << 16) |
      ((unsigned long long)__half_as_ushort(__float2half(acc.z)) << 32) |
      ((unsigned long long)__half_as_ushort(__float2half(acc.w)) << 48);
  __builtin_nontemporal_store(o, (unsigned long long*)(aggh + (size_t)node * F) + l);
}

// ---------------- fused: h = agg@W * dni + b; L2-normalize; sigmoid; hg[gid] += h ----------
__global__ __launch_bounds__(256) void gemm_epi_kernel(
    const __half* __restrict__ agg1, const float* __restrict__ dni1,
    const int* __restrict__ gid1, float* __restrict__ hg1,
    const __half* __restrict__ agg2, const float* __restrict__ dni2,
    const int* __restrict__ gid2, float* __restrict__ hg2,
    const float* __restrict__ Wg, const float* __restrict__ bg, int N) {
  const __half* agg = blockIdx.y ? agg2 : agg1;
  const float* dni = blockIdx.y ? dni2 : dni1;
  const int* gid = blockIdx.y ? gid2 : gid1;
  float* hg = blockIdx.y ? hg2 : hg1;

  __shared__ float Wl[F * F];
  __shared__ float Al[TM * F];
  __shared__ float hred[4][F];
  int tid = threadIdx.x;

  const float4* Wv = (const float4*)Wg;
  float4* Wlv = (float4*)Wl;
#pragma unroll
  for (int i = 0; i < (F * F / 4) / 256; ++i)
    Wlv[tid + i * 256] = Wv[tid + i * 256];

  int r0 = blockIdx.x * TM;
  const unsigned long long* Av = (const unsigned long long*)(agg + (size_t)r0 * F);
  float4* Alv = (float4*)Al;
#pragma unroll
  for (int i = 0; i < (TM * F / 4) / 256; ++i) {
    unsigned long long rv = Av[tid + i * 256];
    union { unsigned long long u; __half2 h[2]; } U; U.u = rv;
    float2 f0 = __half22float2(U.h[0]);
    float2 f1 = __half22float2(U.h[1]);
    Alv[tid + i * 256] = make_float4(f0.x, f0.y, f1.x, f1.y);
  }
  __syncthreads();

  int rg = tid >> 5;   // 0..7  (4 rows each)
  int cg = tid & 31;   // 0..31 (4 cols each)

  float acc[4][4];
#pragma unroll
  for (int i = 0; i < 4; ++i)
#pragma unroll
    for (int j = 0; j < 4; ++j) acc[i][j] = 0.0f;

  for (int k0 = 0; k0 < F; k0 += 4) {
    float4 a4[4];
#pragma unroll
    for (int i = 0; i < 4; ++i)
      a4[i] = *(const float4*)&Al[(rg * 4 + i) * F + k0];
#pragma unroll
    for (int kk = 0; kk < 4; ++kk) {
      float4 wv = *(const float4*)&Wl[(k0 + kk) * F + cg * 4];
#pragma unroll
      for (int i = 0; i < 4; ++i) {
        float av = ((const float*)&a4[i])[kk];
        acc[i][0] += av * wv.x;
        acc[i][1] += av * wv.y;
        acc[i][2] += av * wv.z;
        acc[i][3] += av * wv.w;
      }
    }
  }

  float dnr[4];
  int gg[4];
#pragma unroll
  for (int i = 0; i < 4; ++i) {
    int r = r0 + rg * 4 + i;
    dnr[i] = dni[r];
    gg[i] = gid[r];
  }
  float4 bb = *(const float4*)(bg + cg * 4);
  const float* bbf = (const float*)&bb;

  float y[4][4], ssq[4];
#pragma unroll
  for (int i = 0; i < 4; ++i) {
    ssq[i] = 0.0f;
#pragma unroll
    for (int j = 0; j < 4; ++j) {
      float t = acc[i][j] * dnr[i] + bbf[j];
      y[i][j] = t;
      ssq[i] += t * t;
    }
  }
#pragma unroll
  for (int m = 1; m < 32; m <<= 1) {
#pragma unroll
    for (int i = 0; i < 4; ++i) ssq[i] += __shfl_xor(ssq[i], m);
  }

  float u[4][4];
#pragma unroll
  for (int i = 0; i < 4; ++i) {
    float inv = 1.0f / fmaxf(sqrtf(ssq[i]), 1e-12f);
#pragma unroll
    for (int j = 0; j < 4; ++j)
      u[i][j] = 1.0f / (1.0f + expf(-y[i][j] * inv));  // relu(sigmoid(x)) == sigmoid(x)
  }

  int lane = tid & 63;
  int wv_id = tid >> 6;
  int g_first = gid[r0];
  int g_last = gid[r0 + TM - 1];
  if (g_first == g_last) {
    float cs[4];
#pragma unroll
    for (int j = 0; j < 4; ++j) {
      cs[j] = u[0][j] + u[1][j] + u[2][j] + u[3][j];
      cs[j] += __shfl_xor(cs[j], 32);
    }
    if (lane < 32) {
#pragma unroll
      for (int j = 0; j < 4; ++j) hred[wv_id][cg * 4 + j] = cs[j];
    }
    __syncthreads();
    if (tid < F) {
      float s = hred[0][tid] + hred[1][tid] + hred[2][tid] + hred[3][tid];
      atomicAddF(&hg[(size_t)g_first * F + tid], s);
    }
  } else {
    int g0 = gid[r0 + wv_id * 8];
    bool ok = (gg[0] == g0) && (gg[1] == g0) && (gg[2] == g0) && (gg[3] == g0);
    if (__all(ok)) {
      float cs[4];
#pragma unroll
      for (int j = 0; j < 4; ++j) {
        cs[j] = u[0][j] + u[1][j] + u[2][j] + u[3][j];
        cs[j] += __shfl_xor(cs[j], 32);
      }
      if (lane < 32) {
#pragma unroll
        for (int j = 0; j < 4; ++j)
          atomicAddF(&hg[(size_t)g0 * F + cg * 4 + j], cs[j]);
      }
    } else {
#pragma unroll
      for (int i = 0; i < 4; ++i)
#pragma unroll
        for (int j = 0; j < 4; ++j)
          atomicAddF(&hg[(size_t)gg[i] * F + cg * 4 + j], u[i][j]);
    }
  }
}

// ---------------- final ----------------
__global__ __launch_bounds__(64) void final_kernel(
    const float* __restrict__ hg1, const int* __restrict__ cnt1,
    const float* __restrict__ hg2, const int* __restrict__ cnt2,
    const float* __restrict__ Wc, const float* __restrict__ bc,
    float* __restrict__ out) {
  __shared__ float v1[F], v2[F];
  int g = blockIdx.x, c = threadIdx.x;
  float ic1 = 1.0f / fmaxf((float)cnt1[g], 1.0f);
  float ic2 = 1.0f / fmaxf((float)cnt2[g], 1.0f);
  for (int i = c; i < F; i += 64) {
    v1[i] = hg1[(size_t)g * F + i] * ic1;
    v2[i] = hg2[(size_t)g * F + i] * ic2;
  }
  __syncthreads();
  float z1 = bc[c], z2 = bc[c];
  for (int k = 0; k < F; ++k) {
    float w = Wc[k * C + c];
    z1 += v1[k] * w;
    z2 += v2[k] * w;
  }
  float d = z1 - z2 + 1e-6f;
  d *= d;
#pragma unroll
  for (int m = 1; m < 64; m <<= 1) d += __shfl_xor(d, m);
  if (c == 0) out[g] = sqrtf(d);
}

extern "C" void kernel_launch(void* const* d_in, const int* in_sizes, int n_in,
                              void* d_out, int out_size, void* d_ws, size_t ws_size,
                              hipStream_t stream) {
  const float* feat1 = (const float*)d_in[0];
  const float* feat2 = (const float*)d_in[1];
  const int* src1 = (const int*)d_in[2];
  const int* dst1 = (const int*)d_in[3];
  const int* gid1 = (const int*)d_in[4];
  const int* src2 = (const int*)d_in[5];
  const int* dst2 = (const int*)d_in[6];
  const int* gid2 = (const int*)d_in[7];
  const float* Wg = (const float*)d_in[8];
  const float* bg = (const float*)d_in[9];
  const float* Wc = (const float*)d_in[10];
  const float* bc = (const float*)d_in[11];
  float* out = (float*)d_out;

  int N = in_sizes[0] / F;
  int E = in_sizes[2];
  int K = (N + 255) >> 8;           // coarse buckets (391 for N=100000)
  if (K > KMAX) return;             // unsupported size: fail loudly

  // ---- workspace layout: zero-init region first (all sizes multiples of 16B) ----
  char* w = (char*)d_ws;
  int* dego1 = (int*)w; w += (size_t)N * 4;
  int* dego2 = (int*)w; w += (size_t)N * 4;
  float* hg1 = (float*)w; w += (size_t)G * F * 4;
  float* hg2 = (float*)w; w += (size_t)G * F * 4;
  int* bcnt1 = (int*)w; w += KMAX * 4;
  int* bcnt2 = (int*)w; w += KMAX * 4;
  size_t zbytes = (size_t)(w - (char*)d_ws);
  // non-zeroed scratch:
  __half* aggh1 = (__half*)w; w += (size_t)N * F * 2;
  __half* aggh2 = (__half*)w; w += (size_t)N * F * 2;
  __half* fs1 = (__half*)w; w += (size_t)N * F * 2;
  __half* fs2 = (__half*)w; w += (size_t)N * F * 2;
  unsigned* epk1 = (unsigned*)w; w += (size_t)E * 4;   // pass1 packed; pass2 rewrites as esrc
  unsigned* epk2 = (unsigned*)w; w += (size_t)E * 4;
  int* degi1 = (int*)w; w += (size_t)N * 4;
  int* degi2 = (int*)w; w += (size_t)N * 4;
  float* dni1 = (float*)w; w += (size_t)N * 4;
  float* dni2 = (float*)w; w += (size_t)N * 4;
  int* cursor1 = (int*)w; w += (size_t)N * 4;
  int* cursor2 = (int*)w; w += (size_t)N * 4;
  int* cnt1 = (int*)w; w += 128 * 4;
  int* cnt2 = (int*)w; w += 128 * 4;
  int* bstart1 = (int*)w; w += (KMAX + 4) * 4;
  int* bstart2 = (int*)w; w += (KMAX + 4) * 4;
  int* bcur1 = (int*)w; w += KMAX * 4;
  int* bcur2 = (int*)w; w += KMAX * 4;
  if ((size_t)(w - (char*)d_ws) > ws_size) return;  // fail loudly (output stays poisoned)

  (void)hipMemsetAsync(d_ws, 0, zbytes, stream);

  int eb = (E + 255) / 256;
  deg_kernel<<<dim3(eb, 2), 256, 0, stream>>>(src1, src2, dego1, dego2, E);

  int bhb = (E + BHCH - 1) / BHCH;
  bhist_kernel<<<dim3(bhb, 2), 256, 0, stream>>>(dst1, dst2, bcnt1, bcnt2, E, K);
  bscan_kernel<<<2, 512, 0, stream>>>(bcnt1, bcnt2, bstart1, bstart2, bcur1, bcur2, K, E);

  cnt_kernel<<<2, 128, 0, stream>>>(gid1, gid2, cnt1, cnt2, N);

  int p1b = (E + P1CH - 1) / P1CH;
  pass1_kernel<<<dim3(p1b, 2), 256, 0, stream>>>(src1, dst1, src2, dst2,
                                                 bcur1, bcur2, epk1, epk2, E, K);
  pass2_kernel<<<dim3(K, 2), 256, 0, stream>>>(bstart1, bstart2, epk1, epk2,
                                               degi1, degi2, dni1, dni2,
                                               cursor1, cursor2, N);

  // fp16 pre-scaled features (right before gather to maximize L3 residency)
  int fsb = (N * (F / 4) + 255) / 256;
  fscale_kernel<<<dim3(fsb, 2), 256, 0, stream>>>(feat1, feat2, dego1, dego2, fs1, fs2, N);

  // gather per branch sequentially: hot featsc = 25.6 MB -> L3-resident
  int gbr = (N + 7) / 8;
  gather_kernel<<<gbr, 256, 0, stream>>>((const int*)epk1, cursor1, degi1, fs1, aggh1, N);
  gather_kernel<<<gbr, 256, 0, stream>>>((const int*)epk2, cursor2, degi2, fs2, aggh2, N);

  int gb = N / TM;
  gemm_epi_kernel<<<dim3(gb, 2), 256, 0, stream>>>(
      aggh1, dni1, gid1, hg1, aggh2, dni2, gid2, hg2, Wg, bg, N);

  final_kernel<<<G, 64, 0, stream>>>(hg1, cnt1, hg2, cnt2, Wc, bc, out);
}

// Round 7
// 574.774 us; speedup vs baseline: 11.3276x; 1.2765x over previous
//
#include <hip/hip_runtime.h>
#include <hip/hip_fp16.h>
#include <math.h>

// Problem constants: F=IN_FEATS=H2=128, C=N_CLASSES=64, G=N_GRAPHS=128
#define F 128
#define C 64
#define G 128
#define KMAX 512     // max coarse buckets (N <= 131072)
#define P1CH 8192    // edges per block in pass1
#define BHCH 16384   // edges per block in bhist
#define CAP 16384    // max edges per coarse bucket staged in LDS (mean ~4092)

typedef _Float16 f16x8 __attribute__((ext_vector_type(8)));
typedef float f32x4 __attribute__((ext_vector_type(4)));

__device__ __forceinline__ void atomicAddF(float* p, float v) {
  __hip_atomic_fetch_add(p, v, __ATOMIC_RELAXED, __HIP_MEMORY_SCOPE_AGENT);
}

// ---------------- src-side degree counting (direct atomics) ----------------
__global__ void deg_kernel(const int* __restrict__ src1, const int* __restrict__ src2,
                           int* __restrict__ dego1, int* __restrict__ dego2, int E) {
  const int* src = blockIdx.y ? src2 : src1;
  int* dego = blockIdx.y ? dego2 : dego1;
  int i = blockIdx.x * blockDim.x + threadIdx.x;
  if (i < E) atomicAdd(&dego[src[i]], 1);
}

// ---------------- featsc[n][j] = fp16(feat[n][j] * dego[n]^-1/2) ----------------
__global__ __launch_bounds__(256) void fscale_kernel(
    const float* __restrict__ feat1, const float* __restrict__ feat2,
    const int* __restrict__ dego1, const int* __restrict__ dego2,
    __half* __restrict__ fs1, __half* __restrict__ fs2, int N) {
  const float* feat = blockIdx.y ? feat2 : feat1;
  const int* dego = blockIdx.y ? dego2 : dego1;
  __half* fs = blockIdx.y ? fs2 : fs1;
  int i = blockIdx.x * blockDim.x + threadIdx.x;    // over N*F/4
  if (i >= N * (F / 4)) return;
  int node = i >> 5;                                 // F/4 == 32
  int a = dego[node]; if (a < 1) a = 1;
  float dn = 1.0f / sqrtf((float)a);
  float4 v = ((const float4*)feat)[i];
  unsigned short h0 = __half_as_ushort(__float2half(v.x * dn));
  unsigned short h1 = __half_as_ushort(__float2half(v.y * dn));
  unsigned short h2 = __half_as_ushort(__float2half(v.z * dn));
  unsigned short h3 = __half_as_ushort(__float2half(v.w * dn));
  unsigned long long pk = (unsigned long long)h0 | ((unsigned long long)h1 << 16) |
                          ((unsigned long long)h2 << 32) | ((unsigned long long)h3 << 48);
  ((unsigned long long*)fs)[i] = pk;
}

// ---------------- W -> fp16, pre-swizzled into MFMA B-fragment order ----------------
// frag index f = (t*4+ks)*64 + lane ; element j = W[ks*32+(lane>>4)*8+j][t*16+(lane&15)]
__global__ __launch_bounds__(256) void wconv_kernel(const float* __restrict__ Wg,
                                                    _Float16* __restrict__ Wt) {
  int tid = threadIdx.x;
#pragma unroll
  for (int i = 0; i < 8; ++i) {
    int f = tid + i * 256;          // 0..2047
    int lane = f & 63;
    int ks = (f >> 6) & 3;
    int t = f >> 8;
    int n = t * 16 + (lane & 15);
    int k0 = ks * 32 + ((lane >> 4) << 3);
    f16x8 v;
#pragma unroll
    for (int j = 0; j < 8; ++j) v[j] = (_Float16)Wg[(k0 + j) * F + n];
    ((f16x8*)Wt)[f] = v;
  }
}

// ---------------- per-graph node counts via binary search (gid sorted) ----------------
__global__ __launch_bounds__(128) void cnt_kernel(const int* __restrict__ gid1,
                                                  const int* __restrict__ gid2,
                                                  int* __restrict__ cnt1,
                                                  int* __restrict__ cnt2, int N) {
  const int* gid = blockIdx.x ? gid2 : gid1;
  int* cnt = blockIdx.x ? cnt2 : cnt1;
  int g = threadIdx.x;
  int lo = 0, hi = N;
  while (lo < hi) { int m = (lo + hi) >> 1; if (gid[m] < g) lo = m + 1; else hi = m; }
  int lo2 = lo, hi2 = N;
  while (lo2 < hi2) { int m = (lo2 + hi2) >> 1; if (gid[m] <= g) lo2 = m + 1; else hi2 = m; }
  cnt[g] = lo2 - lo;
}

// ---------------- coarse histogram of dst>>8 (LDS-privatized) ----------------
__global__ __launch_bounds__(256) void bhist_kernel(const int* __restrict__ dst1,
                                                    const int* __restrict__ dst2,
                                                    int* __restrict__ bcnt1,
                                                    int* __restrict__ bcnt2, int E, int K) {
  const int* dst = blockIdx.y ? dst2 : dst1;
  int* bcnt = blockIdx.y ? bcnt2 : bcnt1;
  __shared__ int c[KMAX];
  int t = threadIdx.x;
  for (int k = t; k < K; k += 256) c[k] = 0;
  __syncthreads();
  int e0 = blockIdx.x * BHCH;
  int e1 = e0 + BHCH; if (e1 > E) e1 = E;
  for (int i = e0 + t; i < e1; i += 256) atomicAdd(&c[dst[i] >> 8], 1);
  __syncthreads();
  for (int k = t; k < K; k += 256)
    if (c[k]) atomicAdd(&bcnt[k], c[k]);
}

// ---------------- exclusive scan over K coarse buckets (1 block/branch) ----------------
__global__ __launch_bounds__(512) void bscan_kernel(const int* __restrict__ bcnt1,
                                                    const int* __restrict__ bcnt2,
                                                    int* __restrict__ bstart1,
                                                    int* __restrict__ bstart2,
                                                    int* __restrict__ bcur1,
                                                    int* __restrict__ bcur2, int K, int E) {
  const int* bcnt = blockIdx.x ? bcnt2 : bcnt1;
  int* bstart = blockIdx.x ? bstart2 : bstart1;
  int* bcur = blockIdx.x ? bcur2 : bcur1;
  __shared__ int s[512];
  int t = threadIdx.x;
  int v = (t < K) ? bcnt[t] : 0;
  s[t] = v;
  __syncthreads();
  for (int off = 1; off < 512; off <<= 1) {
    int x = (t >= off) ? s[t - off] : 0;
    __syncthreads();
    s[t] += x;
    __syncthreads();
  }
  int excl = s[t] - v;
  if (t < K) { bstart[t] = excl; bcur[t] = excl; }
  if (t == 0) bstart[K] = E;
}

// ---------------- pass1: bin edges into coarse buckets, packed (dst&255)<<24 | src ----------
__global__ __launch_bounds__(256) void pass1_kernel(
    const int* __restrict__ src1, const int* __restrict__ dst1,
    const int* __restrict__ src2, const int* __restrict__ dst2,
    int* __restrict__ bcur1, int* __restrict__ bcur2,
    unsigned* __restrict__ epk1, unsigned* __restrict__ epk2, int E, int K) {
  const int* src = blockIdx.y ? src2 : src1;
  const int* dst = blockIdx.y ? dst2 : dst1;
  int* bcur = blockIdx.y ? bcur2 : bcur1;
  unsigned* epk = blockIdx.y ? epk2 : epk1;

  __shared__ int cnt[KMAX], base[KMAX], cnt2[KMAX];
  int t = threadIdx.x;
  for (int k = t; k < K; k += 256) { cnt[k] = 0; cnt2[k] = 0; }
  __syncthreads();
  int e0 = blockIdx.x * P1CH;
  int e1 = e0 + P1CH; if (e1 > E) e1 = E;
  for (int i = e0 + t; i < e1; i += 256)
    atomicAdd(&cnt[dst[i] >> 8], 1);
  __syncthreads();
  for (int k = t; k < K; k += 256) {
    int c = cnt[k];
    if (c) base[k] = atomicAdd(&bcur[k], c);
  }
  __syncthreads();
  for (int i = e0 + t; i < e1; i += 256) {
    int d = dst[i];
    int k = d >> 8;
    int r = atomicAdd(&cnt2[k], 1);
    epk[base[k] + r] = ((unsigned)(d & 255) << 24) | (unsigned)src[i];
  }
}

// ---------------- pass2: bucket-local fine sort; emits degi/dni/cursor + esrc in-place ------
__global__ __launch_bounds__(256) void pass2_kernel(
    const int* __restrict__ bstart1, const int* __restrict__ bstart2,
    unsigned* __restrict__ epk1, unsigned* __restrict__ epk2,
    int* __restrict__ degi1, int* __restrict__ degi2,
    float* __restrict__ dni1, float* __restrict__ dni2,
    int* __restrict__ cursor1, int* __restrict__ cursor2, int N) {
  const int* bstart = blockIdx.y ? bstart2 : bstart1;
  unsigned* epk = blockIdx.y ? epk2 : epk1;   // also the esrc output (in-place)
  int* degi = blockIdx.y ? degi2 : degi1;
  float* dni = blockIdx.y ? dni2 : dni1;
  int* cursor = blockIdx.y ? cursor2 : cursor1;

  __shared__ unsigned pk[CAP];
  __shared__ int lcnt[256];
  __shared__ int lcur[256];

  int b = blockIdx.x;
  int t = threadIdx.x;
  int s0 = bstart[b], s1 = bstart[b + 1];
  int M = s1 - s0;

  lcnt[t] = 0;
  for (int e = t; e < M; e += 256) pk[e] = epk[s0 + e];
  __syncthreads();
  for (int e = t; e < M; e += 256) atomicAdd(&lcnt[pk[e] >> 24], 1);
  __syncthreads();

  int v = lcnt[t];
  lcur[t] = v;
  __syncthreads();
  for (int off = 1; off < 256; off <<= 1) {
    int x = (t >= off) ? lcur[t - off] : 0;
    __syncthreads();
    lcur[t] += x;
    __syncthreads();
  }
  int excl = lcur[t] - v;
  int startp = s0 + excl;
  int node = (b << 8) + t;
  if (node < N) {
    degi[node] = v;
    int vc = v < 1 ? 1 : v;
    dni[node] = 1.0f / sqrtf((float)vc);
    cursor[node] = startp;
  }
  __syncthreads();
  lcur[t] = startp;
  __syncthreads();
  for (int e = t; e < M; e += 256) {
    unsigned p = pk[e];
    int dl = p >> 24;
    int pos = atomicAdd(&lcur[dl], 1);
    epk[pos] = p & 0xFFFFFFu;   // esrc value (node id < 2^17)
  }
}

// ---------------- gather-reduce: agg[d] = sum over in-edges of featsc[s] (fp16 rows) -------
__global__ __launch_bounds__(256) void gather_kernel(
    const int* __restrict__ esrc, const int* __restrict__ cursor,
    const int* __restrict__ degi, const __half* __restrict__ featsc,
    __half* __restrict__ aggh, int N) {
  int node = blockIdx.x * 8 + (threadIdx.x >> 5);
  int l = threadIdx.x & 31;
  if (node >= N) return;
  int cnt = degi[node];
  int start = cursor[node];
  float4 acc = {0.f, 0.f, 0.f, 0.f};
  for (int j0 = 0; j0 < cnt; j0 += 32) {
    int nb = cnt - j0; if (nb > 32) nb = 32;
    int myi = (l < nb) ? __builtin_nontemporal_load(&esrc[start + j0 + l]) : 0;
#pragma unroll 4
    for (int k = 0; k < nb; ++k) {
      int s = __shfl(myi, k, 32);
      unsigned long long rv = ((const unsigned long long*)(featsc + (size_t)s * F))[l];
      union { unsigned long long u; __half2 h[2]; } U; U.u = rv;
      float2 f0 = __half22float2(U.h[0]);
      float2 f1 = __half22float2(U.h[1]);
      acc.x += f0.x; acc.y += f0.y; acc.z += f1.x; acc.w += f1.y;
    }
  }
  unsigned long long o =
      (unsigned long long)__half_as_ushort(__float2half(acc.x)) |
      ((unsigned long long)__half_as_ushort(__float2half(acc.y)) << 16) |
      ((unsigned long long)__half_as_ushort(__float2half(acc.z)) << 32) |
      ((unsigned long long)__half_as_ushort(__float2half(acc.w)) << 48);
  __builtin_nontemporal_store(o, (unsigned long long*)(aggh + (size_t)node * F) + l);
}

// ---------------- MFMA gemm + epilogue ----------------
// Block = 256 threads (4 waves), 64 rows/block (16 rows/wave), full 128 cols.
// h = aggh@W (fp16 MFMA, fp32 acc) * dni + b; L2-normalize; sigmoid; hg[gid] += h.
__global__ __launch_bounds__(256) void gemm_epi_kernel(
    const __half* __restrict__ agg1, const float* __restrict__ dni1,
    const int* __restrict__ gid1, float* __restrict__ hg1,
    const __half* __restrict__ agg2, const float* __restrict__ dni2,
    const int* __restrict__ gid2, float* __restrict__ hg2,
    const _Float16* __restrict__ Wt, const float* __restrict__ bg, int N) {
  const __half* agg = blockIdx.y ? agg2 : agg1;
  const float* dni = blockIdx.y ? dni2 : dni1;
  const int* gid = blockIdx.y ? gid2 : gid1;
  float* hg = blockIdx.y ? hg2 : hg1;

  __shared__ __align__(16) _Float16 Wl[16384];   // 32KB, B-fragment order
  __shared__ float hred[4][F];
  __shared__ int sgid[4];

  int tid = threadIdx.x;
  int wv = tid >> 6;
  int lane = tid & 63;
  int ln = lane & 15;
  int quad = lane >> 4;

  // stage swizzled W (coalesced 16B copies)
  {
    const f16x8* src = (const f16x8*)Wt;
    f16x8* dst = (f16x8*)Wl;
#pragma unroll
    for (int i = 0; i < 8; ++i) dst[tid + i * 256] = src[tid + i * 256];
  }
  __syncthreads();

  int rbase = (blockIdx.x * 4 + wv) * 16;
  bool wave_active = rbase < N;

  // A fragments: row = rbase + ln (clamped), k = ks*32 + quad*8 + j
  int arow = rbase + ln; if (arow >= N) arow = N - 1;
  const _Float16* arow_p = (const _Float16*)(agg + (size_t)arow * F);
  f16x8 a[4];
#pragma unroll
  for (int ks = 0; ks < 4; ++ks)
    a[ks] = *(const f16x8*)(arow_p + ks * 32 + quad * 8);

  f32x4 acc[8];
#pragma unroll
  for (int t = 0; t < 8; ++t) acc[t] = (f32x4){0.f, 0.f, 0.f, 0.f};

#pragma unroll
  for (int t = 0; t < 8; ++t) {
#pragma unroll
    for (int ks = 0; ks < 4; ++ks) {
      f16x8 b = *(const f16x8*)&Wl[(((t << 2) + ks) * 64 + lane) * 8];
      acc[t] = __builtin_amdgcn_mfma_f32_16x16x32_f16(a[ks], b, acc[t], 0, 0, 0);
    }
  }

  // epilogue: lane holds rows rbase+quad*4+r (r=0..3), cols t*16+ln (t=0..7)
  float dnr[4]; int gg[4]; bool valid[4];
#pragma unroll
  for (int r = 0; r < 4; ++r) {
    int row = rbase + quad * 4 + r;
    valid[r] = row < N;
    int rc = valid[r] ? row : (N - 1);
    dnr[r] = dni[rc];
    gg[r] = gid[rc];
  }
  float bb[8];
#pragma unroll
  for (int t = 0; t < 8; ++t) bb[t] = bg[t * 16 + ln];

  float y[8][4], ssq[4];
#pragma unroll
  for (int r = 0; r < 4; ++r) ssq[r] = 0.f;
#pragma unroll
  for (int t = 0; t < 8; ++t) {
#pragma unroll
    for (int r = 0; r < 4; ++r) {
      float v = acc[t][r] * dnr[r] + bb[t];
      y[t][r] = v;
      ssq[r] += v * v;
    }
  }
  // reduce ssq across the 16 lanes of the quad (lane bits 0..3)
#pragma unroll
  for (int m = 1; m < 16; m <<= 1) {
#pragma unroll
    for (int r = 0; r < 4; ++r) ssq[r] += __shfl_xor(ssq[r], m);
  }
  float u[8][4];
#pragma unroll
  for (int r = 0; r < 4; ++r) {
    float inv = 1.0f / fmaxf(sqrtf(ssq[r]), 1e-12f);
#pragma unroll
    for (int t = 0; t < 8; ++t) {
      float s = 1.0f / (1.0f + expf(-y[t][r] * inv));  // relu(sigmoid) == sigmoid
      u[t][r] = valid[r] ? s : 0.0f;
    }
  }

  // per-graph accumulation
  int rlast = rbase + 15; if (rlast >= N) rlast = N - 1;
  bool uniform = wave_active && (rbase + 15 < N) && (gid[rbase] == gid[rlast]);
  if (uniform) {
    float cs[8];
#pragma unroll
    for (int t = 0; t < 8; ++t) {
      cs[t] = u[t][0] + u[t][1] + u[t][2] + u[t][3];
      cs[t] += __shfl_xor(cs[t], 16);
      cs[t] += __shfl_xor(cs[t], 32);
    }
    if (lane == 0) sgid[wv] = gid[rbase];
    if (lane < 16) {
#pragma unroll
      for (int t = 0; t < 8; ++t) hred[wv][t * 16 + lane] = cs[t];
    }
  } else {
    if (lane == 0) sgid[wv] = -1;
    if (wave_active) {
#pragma unroll
      for (int r = 0; r < 4; ++r) {
        if (!valid[r]) continue;
#pragma unroll
        for (int t = 0; t < 8; ++t)
          atomicAddF(&hg[(size_t)gg[r] * F + t * 16 + ln], u[t][r]);
      }
    }
  }
  __syncthreads();
  if (tid < F) {
    int s0 = sgid[0], s1 = sgid[1], s2 = sgid[2], s3 = sgid[3];
    if (s0 >= 0 && s0 == s1 && s0 == s2 && s0 == s3) {
      atomicAddF(&hg[(size_t)s0 * F + tid],
                 hred[0][tid] + hred[1][tid] + hred[2][tid] + hred[3][tid]);
    } else {
      if (s0 >= 0) atomicAddF(&hg[(size_t)s0 * F + tid], hred[0][tid]);
      if (s1 >= 0) atomicAddF(&hg[(size_t)s1 * F + tid], hred[1][tid]);
      if (s2 >= 0) atomicAddF(&hg[(size_t)s2 * F + tid], hred[2][tid]);
      if (s3 >= 0) atomicAddF(&hg[(size_t)s3 * F + tid], hred[3][tid]);
    }
  }
}

// ---------------- final ----------------
__global__ __launch_bounds__(64) void final_kernel(
    const float* __restrict__ hg1, const int* __restrict__ cnt1,
    const float* __restrict__ hg2, const int* __restrict__ cnt2,
    const float* __restrict__ Wc, const float* __restrict__ bc,
    float* __restrict__ out) {
  __shared__ float v1[F], v2[F];
  int g = blockIdx.x, c = threadIdx.x;
  float ic1 = 1.0f / fmaxf((float)cnt1[g], 1.0f);
  float ic2 = 1.0f / fmaxf((float)cnt2[g], 1.0f);
  for (int i = c; i < F; i += 64) {
    v1[i] = hg1[(size_t)g * F + i] * ic1;
    v2[i] = hg2[(size_t)g * F + i] * ic2;
  }
  __syncthreads();
  float z1 = bc[c], z2 = bc[c];
  for (int k = 0; k < F; ++k) {
    float w = Wc[k * C + c];
    z1 += v1[k] * w;
    z2 += v2[k] * w;
  }
  float d = z1 - z2 + 1e-6f;
  d *= d;
#pragma unroll
  for (int m = 1; m < 64; m <<= 1) d += __shfl_xor(d, m);
  if (c == 0) out[g] = sqrtf(d);
}

extern "C" void kernel_launch(void* const* d_in, const int* in_sizes, int n_in,
                              void* d_out, int out_size, void* d_ws, size_t ws_size,
                              hipStream_t stream) {
  const float* feat1 = (const float*)d_in[0];
  const float* feat2 = (const float*)d_in[1];
  const int* src1 = (const int*)d_in[2];
  const int* dst1 = (const int*)d_in[3];
  const int* gid1 = (const int*)d_in[4];
  const int* src2 = (const int*)d_in[5];
  const int* dst2 = (const int*)d_in[6];
  const int* gid2 = (const int*)d_in[7];
  const float* Wg = (const float*)d_in[8];
  const float* bg = (const float*)d_in[9];
  const float* Wc = (const float*)d_in[10];
  const float* bc = (const float*)d_in[11];
  float* out = (float*)d_out;

  int N = in_sizes[0] / F;
  int E = in_sizes[2];
  int K = (N + 255) >> 8;           // coarse buckets (391 for N=100000)
  if (K > KMAX) return;             // unsupported size: fail loudly

  // ---- workspace layout: zero-init region first (all sizes multiples of 16B) ----
  char* w = (char*)d_ws;
  int* dego1 = (int*)w; w += (size_t)N * 4;
  int* dego2 = (int*)w; w += (size_t)N * 4;
  float* hg1 = (float*)w; w += (size_t)G * F * 4;
  float* hg2 = (float*)w; w += (size_t)G * F * 4;
  int* bcnt1 = (int*)w; w += KMAX * 4;
  int* bcnt2 = (int*)w; w += KMAX * 4;
  size_t zbytes = (size_t)(w - (char*)d_ws);
  // non-zeroed scratch:
  __half* aggh1 = (__half*)w; w += (size_t)N * F * 2;
  __half* aggh2 = (__half*)w; w += (size_t)N * F * 2;
  __half* fs1 = (__half*)w; w += (size_t)N * F * 2;
  __half* fs2 = (__half*)w; w += (size_t)N * F * 2;
  unsigned* epk1 = (unsigned*)w; w += (size_t)E * 4;   // pass1 packed; pass2 rewrites as esrc
  unsigned* epk2 = (unsigned*)w; w += (size_t)E * 4;
  int* degi1 = (int*)w; w += (size_t)N * 4;
  int* degi2 = (int*)w; w += (size_t)N * 4;
  float* dni1 = (float*)w; w += (size_t)N * 4;
  float* dni2 = (float*)w; w += (size_t)N * 4;
  int* cursor1 = (int*)w; w += (size_t)N * 4;
  int* cursor2 = (int*)w; w += (size_t)N * 4;
  int* cnt1 = (int*)w; w += 128 * 4;
  int* cnt2 = (int*)w; w += 128 * 4;
  int* bstart1 = (int*)w; w += (KMAX + 4) * 4;
  int* bstart2 = (int*)w; w += (KMAX + 4) * 4;
  int* bcur1 = (int*)w; w += KMAX * 4;
  int* bcur2 = (int*)w; w += KMAX * 4;
  _Float16* Wt = (_Float16*)w; w += (size_t)F * F * 2;  // swizzled fp16 W
  if ((size_t)(w - (char*)d_ws) > ws_size) return;  // fail loudly (output stays poisoned)

  (void)hipMemsetAsync(d_ws, 0, zbytes, stream);

  wconv_kernel<<<1, 256, 0, stream>>>(Wg, Wt);

  int eb = (E + 255) / 256;
  deg_kernel<<<dim3(eb, 2), 256, 0, stream>>>(src1, src2, dego1, dego2, E);

  int bhb = (E + BHCH - 1) / BHCH;
  bhist_kernel<<<dim3(bhb, 2), 256, 0, stream>>>(dst1, dst2, bcnt1, bcnt2, E, K);
  bscan_kernel<<<2, 512, 0, stream>>>(bcnt1, bcnt2, bstart1, bstart2, bcur1, bcur2, K, E);

  cnt_kernel<<<2, 128, 0, stream>>>(gid1, gid2, cnt1, cnt2, N);

  int p1b = (E + P1CH - 1) / P1CH;
  pass1_kernel<<<dim3(p1b, 2), 256, 0, stream>>>(src1, dst1, src2, dst2,
                                                 bcur1, bcur2, epk1, epk2, E, K);
  pass2_kernel<<<dim3(K, 2), 256, 0, stream>>>(bstart1, bstart2, epk1, epk2,
                                               degi1, degi2, dni1, dni2,
                                               cursor1, cursor2, N);

  // fp16 pre-scaled features (right before gather to maximize L3 residency)
  int fsb = (N * (F / 4) + 255) / 256;
  fscale_kernel<<<dim3(fsb, 2), 256, 0, stream>>>(feat1, feat2, dego1, dego2, fs1, fs2, N);

  // gather per branch sequentially: hot featsc = 25.6 MB -> L3-resident
  int gbr = (N + 7) / 8;
  gather_kernel<<<gbr, 256, 0, stream>>>((const int*)epk1, cursor1, degi1, fs1, aggh1, N);
  gather_kernel<<<gbr, 256, 0, stream>>>((const int*)epk2, cursor2, degi2, fs2, aggh2, N);

  int gb = (N + 63) / 64;
  gemm_epi_kernel<<<dim3(gb, 2), 256, 0, stream>>>(
      aggh1, dni1, gid1, hg1, aggh2, dni2, gid2, hg2, Wt, bg, N);

  final_kernel<<<G, 64, 0, stream>>>(hg1, cnt1, hg2, cnt2, Wc, bc, out);
}

// Round 8
// 513.403 us; speedup vs baseline: 12.6816x; 1.1195x over previous
//
#include <hip/hip_runtime.h>
#include <hip/hip_fp16.h>
#include <math.h>

// Problem constants: F=IN_FEATS=H2=128, C=N_CLASSES=64, G=N_GRAPHS=128
#define F 128
#define C 64
#define G 128
#define KMAX 512     // max coarse buckets (N <= 131072)
#define P1CH 8192    // edges per block in pass1
#define BHCH 16384   // edges per block in bhist
#define CAP 16384    // max edges per coarse bucket staged in LDS (mean ~4092)

typedef _Float16 f16x8 __attribute__((ext_vector_type(8)));
typedef float f32x4 __attribute__((ext_vector_type(4)));

__device__ __forceinline__ void atomicAddF(float* p, float v) {
  __hip_atomic_fetch_add(p, v, __ATOMIC_RELAXED, __HIP_MEMORY_SCOPE_AGENT);
}

// ---------------- featsc[n][j] = fp16(feat[n][j] * dno[n]) ----------------
__global__ __launch_bounds__(256) void fscale_kernel(
    const float* __restrict__ feat1, const float* __restrict__ feat2,
    const float* __restrict__ dno1, const float* __restrict__ dno2,
    __half* __restrict__ fs1, __half* __restrict__ fs2, int N) {
  const float* feat = blockIdx.y ? feat2 : feat1;
  const float* dno = blockIdx.y ? dno2 : dno1;
  __half* fs = blockIdx.y ? fs2 : fs1;
  int i = blockIdx.x * blockDim.x + threadIdx.x;    // over N*F/4
  if (i >= N * (F / 4)) return;
  int node = i >> 5;                                 // F/4 == 32
  float dn = dno[node];
  float4 v = ((const float4*)feat)[i];
  unsigned short h0 = __half_as_ushort(__float2half(v.x * dn));
  unsigned short h1 = __half_as_ushort(__float2half(v.y * dn));
  unsigned short h2 = __half_as_ushort(__float2half(v.z * dn));
  unsigned short h3 = __half_as_ushort(__float2half(v.w * dn));
  unsigned long long pk = (unsigned long long)h0 | ((unsigned long long)h1 << 16) |
                          ((unsigned long long)h2 << 32) | ((unsigned long long)h3 << 48);
  ((unsigned long long*)fs)[i] = pk;
}

// ---------------- W -> fp16, pre-swizzled into MFMA B-fragment order ----------------
__global__ __launch_bounds__(256) void wconv_kernel(const float* __restrict__ Wg,
                                                    _Float16* __restrict__ Wt) {
  int tid = threadIdx.x;
#pragma unroll
  for (int i = 0; i < 8; ++i) {
    int f = tid + i * 256;          // 0..2047
    int lane = f & 63;
    int ks = (f >> 6) & 3;
    int t = f >> 8;
    int n = t * 16 + (lane & 15);
    int k0 = ks * 32 + ((lane >> 4) << 3);
    f16x8 v;
#pragma unroll
    for (int j = 0; j < 8; ++j) v[j] = (_Float16)Wg[(k0 + j) * F + n];
    ((f16x8*)Wt)[f] = v;
  }
}

// ---------------- per-graph node counts via binary search (gid sorted) ----------------
__global__ __launch_bounds__(128) void cnt_kernel(const int* __restrict__ gid1,
                                                  const int* __restrict__ gid2,
                                                  int* __restrict__ cnt1,
                                                  int* __restrict__ cnt2, int N) {
  const int* gid = blockIdx.x ? gid2 : gid1;
  int* cnt = blockIdx.x ? cnt2 : cnt1;
  int g = threadIdx.x;
  int lo = 0, hi = N;
  while (lo < hi) { int m = (lo + hi) >> 1; if (gid[m] < g) lo = m + 1; else hi = m; }
  int lo2 = lo, hi2 = N;
  while (lo2 < hi2) { int m = (lo2 + hi2) >> 1; if (gid[m] <= g) lo2 = m + 1; else hi2 = m; }
  cnt[g] = lo2 - lo;
}

// ---------------- coarse histograms of dst>>8 AND src>>8 (LDS-privatized) ----------------
__global__ __launch_bounds__(256) void bhist_kernel(
    const int* __restrict__ src1, const int* __restrict__ dst1,
    const int* __restrict__ src2, const int* __restrict__ dst2,
    int* __restrict__ bcntD1, int* __restrict__ bcntD2,
    int* __restrict__ bcntS1, int* __restrict__ bcntS2, int E, int K) {
  const int* src = blockIdx.y ? src2 : src1;
  const int* dst = blockIdx.y ? dst2 : dst1;
  int* bcntD = blockIdx.y ? bcntD2 : bcntD1;
  int* bcntS = blockIdx.y ? bcntS2 : bcntS1;
  __shared__ int cD[KMAX], cS[KMAX];
  int t = threadIdx.x;
  for (int k = t; k < K; k += 256) { cD[k] = 0; cS[k] = 0; }
  __syncthreads();
  int e0 = blockIdx.x * BHCH;
  int e1 = e0 + BHCH; if (e1 > E) e1 = E;
  for (int i = e0 + t; i < e1; i += 256) {
    atomicAdd(&cD[dst[i] >> 8], 1);
    atomicAdd(&cS[src[i] >> 8], 1);
  }
  __syncthreads();
  for (int k = t; k < K; k += 256) {
    if (cD[k]) atomicAdd(&bcntD[k], cD[k]);
    if (cS[k]) atomicAdd(&bcntS[k], cS[k]);
  }
}

// ---------------- exclusive scans over K coarse buckets (4 blocks: D1,D2,S1,S2) ----------
__global__ __launch_bounds__(512) void bscan_kernel(
    const int* __restrict__ bcntD1, const int* __restrict__ bcntD2,
    const int* __restrict__ bcntS1, const int* __restrict__ bcntS2,
    int* __restrict__ bstartD1, int* __restrict__ bstartD2,
    int* __restrict__ bstartS1, int* __restrict__ bstartS2,
    int* __restrict__ bcurD1, int* __restrict__ bcurD2,
    int* __restrict__ bcurS1, int* __restrict__ bcurS2, int K, int E) {
  int x = blockIdx.x;
  const int* bcnt = (x == 0) ? bcntD1 : (x == 1) ? bcntD2 : (x == 2) ? bcntS1 : bcntS2;
  int* bstart = (x == 0) ? bstartD1 : (x == 1) ? bstartD2 : (x == 2) ? bstartS1 : bstartS2;
  int* bcur = (x == 0) ? bcurD1 : (x == 1) ? bcurD2 : (x == 2) ? bcurS1 : bcurS2;
  __shared__ int s[512];
  int t = threadIdx.x;
  int v = (t < K) ? bcnt[t] : 0;
  s[t] = v;
  __syncthreads();
  for (int off = 1; off < 512; off <<= 1) {
    int x2 = (t >= off) ? s[t - off] : 0;
    __syncthreads();
    s[t] += x2;
    __syncthreads();
  }
  int excl = s[t] - v;
  if (t < K) { bstart[t] = excl; bcur[t] = excl; }
  if (t == 0) bstart[K] = E;
}

// ---------------- pass1: bin dst-sort words AND src-count words into bucket runs ----------
__global__ __launch_bounds__(256) void pass1_kernel(
    const int* __restrict__ src1, const int* __restrict__ dst1,
    const int* __restrict__ src2, const int* __restrict__ dst2,
    int* __restrict__ bcurD1, int* __restrict__ bcurD2,
    int* __restrict__ bcurS1, int* __restrict__ bcurS2,
    unsigned* __restrict__ epkD1, unsigned* __restrict__ epkD2,
    unsigned* __restrict__ epkS1, unsigned* __restrict__ epkS2, int E, int K) {
  const int* src = blockIdx.y ? src2 : src1;
  const int* dst = blockIdx.y ? dst2 : dst1;
  int* bcurD = blockIdx.y ? bcurD2 : bcurD1;
  int* bcurS = blockIdx.y ? bcurS2 : bcurS1;
  unsigned* epkD = blockIdx.y ? epkD2 : epkD1;
  unsigned* epkS = blockIdx.y ? epkS2 : epkS1;

  __shared__ int cntD[KMAX], baseD[KMAX], cnt2D[KMAX];
  __shared__ int cntS[KMAX], baseS[KMAX], cnt2S[KMAX];
  int t = threadIdx.x;
  for (int k = t; k < K; k += 256) {
    cntD[k] = 0; cnt2D[k] = 0; cntS[k] = 0; cnt2S[k] = 0;
  }
  __syncthreads();
  int e0 = blockIdx.x * P1CH;
  int e1 = e0 + P1CH; if (e1 > E) e1 = E;
  for (int i = e0 + t; i < e1; i += 256) {
    atomicAdd(&cntD[dst[i] >> 8], 1);
    atomicAdd(&cntS[src[i] >> 8], 1);
  }
  __syncthreads();
  for (int k = t; k < K; k += 256) {
    int c = cntD[k];
    if (c) baseD[k] = atomicAdd(&bcurD[k], c);
    int c2 = cntS[k];
    if (c2) baseS[k] = atomicAdd(&bcurS[k], c2);
  }
  __syncthreads();
  for (int i = e0 + t; i < e1; i += 256) {
    int d = dst[i];
    int s = src[i];
    int kD = d >> 8;
    int rD = atomicAdd(&cnt2D[kD], 1);
    epkD[baseD[kD] + rD] = ((unsigned)(d & 255) << 24) | (unsigned)s;
    int kS = s >> 8;
    int rS = atomicAdd(&cnt2S[kS], 1);
    epkS[baseS[kS] + rS] = (unsigned)(s & 255);
  }
}

// ---------------- pass2: dst-bucket fine sort; emits degi/dni/cursor + esrc in-place ------
__global__ __launch_bounds__(256) void pass2_kernel(
    const int* __restrict__ bstart1, const int* __restrict__ bstart2,
    unsigned* __restrict__ epk1, unsigned* __restrict__ epk2,
    int* __restrict__ degi1, int* __restrict__ degi2,
    float* __restrict__ dni1, float* __restrict__ dni2,
    int* __restrict__ cursor1, int* __restrict__ cursor2, int N) {
  const int* bstart = blockIdx.y ? bstart2 : bstart1;
  unsigned* epk = blockIdx.y ? epk2 : epk1;   // also the esrc output (in-place)
  int* degi = blockIdx.y ? degi2 : degi1;
  float* dni = blockIdx.y ? dni2 : dni1;
  int* cursor = blockIdx.y ? cursor2 : cursor1;

  __shared__ unsigned pk[CAP];
  __shared__ int lcnt[256];
  __shared__ int lcur[256];

  int b = blockIdx.x;
  int t = threadIdx.x;
  int s0 = bstart[b], s1 = bstart[b + 1];
  int M = s1 - s0;

  lcnt[t] = 0;
  for (int e = t; e < M; e += 256) pk[e] = epk[s0 + e];
  __syncthreads();
  for (int e = t; e < M; e += 256) atomicAdd(&lcnt[pk[e] >> 24], 1);
  __syncthreads();

  int v = lcnt[t];
  lcur[t] = v;
  __syncthreads();
  for (int off = 1; off < 256; off <<= 1) {
    int x = (t >= off) ? lcur[t - off] : 0;
    __syncthreads();
    lcur[t] += x;
    __syncthreads();
  }
  int excl = lcur[t] - v;
  int startp = s0 + excl;
  int node = (b << 8) + t;
  if (node < N) {
    degi[node] = v;
    int vc = v < 1 ? 1 : v;
    dni[node] = 1.0f / sqrtf((float)vc);
    cursor[node] = startp;
  }
  __syncthreads();
  lcur[t] = startp;
  __syncthreads();
  for (int e = t; e < M; e += 256) {
    unsigned p = pk[e];
    int dl = p >> 24;
    int pos = atomicAdd(&lcur[dl], 1);
    epk[pos] = p & 0xFFFFFFu;   // esrc value (node id < 2^17)
  }
}

// ---------------- pass2c: src-bucket fine histogram -> dno only ----------------
__global__ __launch_bounds__(256) void pass2c_kernel(
    const int* __restrict__ bstart1, const int* __restrict__ bstart2,
    const unsigned* __restrict__ epk1, const unsigned* __restrict__ epk2,
    float* __restrict__ dno1, float* __restrict__ dno2, int N) {
  const int* bstart = blockIdx.y ? bstart2 : bstart1;
  const unsigned* epk = blockIdx.y ? epk2 : epk1;
  float* dno = blockIdx.y ? dno2 : dno1;

  __shared__ int lcnt[256];
  int b = blockIdx.x;
  int t = threadIdx.x;
  int s0 = bstart[b], s1 = bstart[b + 1];
  int M = s1 - s0;
  lcnt[t] = 0;
  __syncthreads();
  for (int e = t; e < M; e += 256)
    atomicAdd(&lcnt[epk[s0 + e] & 255u], 1);
  __syncthreads();
  int node = (b << 8) + t;
  if (node < N) {
    int a = lcnt[t]; if (a < 1) a = 1;
    dno[node] = 1.0f / sqrtf((float)a);
  }
}

// ---------------- gather-reduce: agg[d] = sum over in-edges of featsc[s] (fp16 rows) -------
__global__ __launch_bounds__(256) void gather_kernel(
    const int* __restrict__ esrc, const int* __restrict__ cursor,
    const int* __restrict__ degi, const __half* __restrict__ featsc,
    __half* __restrict__ aggh, int N) {
  int node = blockIdx.x * 8 + (threadIdx.x >> 5);
  int l = threadIdx.x & 31;
  if (node >= N) return;
  int cnt = degi[node];
  int start = cursor[node];
  float4 acc = {0.f, 0.f, 0.f, 0.f};
  for (int j0 = 0; j0 < cnt; j0 += 32) {
    int nb = cnt - j0; if (nb > 32) nb = 32;
    int myi = (l < nb) ? __builtin_nontemporal_load(&esrc[start + j0 + l]) : 0;
#pragma unroll 4
    for (int k = 0; k < nb; ++k) {
      int s = __shfl(myi, k, 32);
      unsigned long long rv = ((const unsigned long long*)(featsc + (size_t)s * F))[l];
      union { unsigned long long u; __half2 h[2]; } U; U.u = rv;
      float2 f0 = __half22float2(U.h[0]);
      float2 f1 = __half22float2(U.h[1]);
      acc.x += f0.x; acc.y += f0.y; acc.z += f1.x; acc.w += f1.y;
    }
  }
  unsigned long long o =
      (unsigned long long)__half_as_ushort(__float2half(acc.x)) |
      ((unsigned long long)__half_as_ushort(__float2half(acc.y)) << 16) |
      ((unsigned long long)__half_as_ushort(__float2half(acc.z)) << 32) |
      ((unsigned long long)__half_as_ushort(__float2half(acc.w)) << 48);
  __builtin_nontemporal_store(o, (unsigned long long*)(aggh + (size_t)node * F) + l);
}

// ---------------- MFMA gemm + epilogue ----------------
__global__ __launch_bounds__(256) void gemm_epi_kernel(
    const __half* __restrict__ agg1, const float* __restrict__ dni1,
    const int* __restrict__ gid1, float* __restrict__ hg1,
    const __half* __restrict__ agg2, const float* __restrict__ dni2,
    const int* __restrict__ gid2, float* __restrict__ hg2,
    const _Float16* __restrict__ Wt, const float* __restrict__ bg, int N) {
  const __half* agg = blockIdx.y ? agg2 : agg1;
  const float* dni = blockIdx.y ? dni2 : dni1;
  const int* gid = blockIdx.y ? gid2 : gid1;
  float* hg = blockIdx.y ? hg2 : hg1;

  __shared__ __align__(16) _Float16 Wl[16384];   // 32KB, B-fragment order
  __shared__ float hred[4][F];
  __shared__ int sgid[4];

  int tid = threadIdx.x;
  int wv = tid >> 6;
  int lane = tid & 63;
  int ln = lane & 15;
  int quad = lane >> 4;

  {
    const f16x8* src = (const f16x8*)Wt;
    f16x8* dst = (f16x8*)Wl;
#pragma unroll
    for (int i = 0; i < 8; ++i) dst[tid + i * 256] = src[tid + i * 256];
  }
  __syncthreads();

  int rbase = (blockIdx.x * 4 + wv) * 16;
  bool wave_active = rbase < N;

  int arow = rbase + ln; if (arow >= N) arow = N - 1;
  const _Float16* arow_p = (const _Float16*)(agg + (size_t)arow * F);
  f16x8 a[4];
#pragma unroll
  for (int ks = 0; ks < 4; ++ks)
    a[ks] = *(const f16x8*)(arow_p + ks * 32 + quad * 8);

  f32x4 acc[8];
#pragma unroll
  for (int t = 0; t < 8; ++t) acc[t] = (f32x4){0.f, 0.f, 0.f, 0.f};

#pragma unroll
  for (int t = 0; t < 8; ++t) {
#pragma unroll
    for (int ks = 0; ks < 4; ++ks) {
      f16x8 b = *(const f16x8*)&Wl[(((t << 2) + ks) * 64 + lane) * 8];
      acc[t] = __builtin_amdgcn_mfma_f32_16x16x32_f16(a[ks], b, acc[t], 0, 0, 0);
    }
  }

  float dnr[4]; int gg[4]; bool valid[4];
#pragma unroll
  for (int r = 0; r < 4; ++r) {
    int row = rbase + quad * 4 + r;
    valid[r] = row < N;
    int rc = valid[r] ? row : (N - 1);
    dnr[r] = dni[rc];
    gg[r] = gid[rc];
  }
  float bb[8];
#pragma unroll
  for (int t = 0; t < 8; ++t) bb[t] = bg[t * 16 + ln];

  float y[8][4], ssq[4];
#pragma unroll
  for (int r = 0; r < 4; ++r) ssq[r] = 0.f;
#pragma unroll
  for (int t = 0; t < 8; ++t) {
#pragma unroll
    for (int r = 0; r < 4; ++r) {
      float v = acc[t][r] * dnr[r] + bb[t];
      y[t][r] = v;
      ssq[r] += v * v;
    }
  }
#pragma unroll
  for (int m = 1; m < 16; m <<= 1) {
#pragma unroll
    for (int r = 0; r < 4; ++r) ssq[r] += __shfl_xor(ssq[r], m);
  }
  float u[8][4];
#pragma unroll
  for (int r = 0; r < 4; ++r) {
    float inv = 1.0f / fmaxf(sqrtf(ssq[r]), 1e-12f);
#pragma unroll
    for (int t = 0; t < 8; ++t) {
      float s = 1.0f / (1.0f + expf(-y[t][r] * inv));  // relu(sigmoid) == sigmoid
      u[t][r] = valid[r] ? s : 0.0f;
    }
  }

  int rlast = rbase + 15; if (rlast >= N) rlast = N - 1;
  bool uniform = wave_active && (rbase + 15 < N) && (gid[rbase] == gid[rlast]);
  if (uniform) {
    float cs[8];
#pragma unroll
    for (int t = 0; t < 8; ++t) {
      cs[t] = u[t][0] + u[t][1] + u[t][2] + u[t][3];
      cs[t] += __shfl_xor(cs[t], 16);
      cs[t] += __shfl_xor(cs[t], 32);
    }
    if (lane == 0) sgid[wv] = gid[rbase];
    if (lane < 16) {
#pragma unroll
      for (int t = 0; t < 8; ++t) hred[wv][t * 16 + lane] = cs[t];
    }
  } else {
    if (lane == 0) sgid[wv] = -1;
    if (wave_active) {
#pragma unroll
      for (int r = 0; r < 4; ++r) {
        if (!valid[r]) continue;
#pragma unroll
        for (int t = 0; t < 8; ++t)
          atomicAddF(&hg[(size_t)gg[r] * F + t * 16 + ln], u[t][r]);
      }
    }
  }
  __syncthreads();
  if (tid < F) {
    int s0 = sgid[0], s1 = sgid[1], s2 = sgid[2], s3 = sgid[3];
    if (s0 >= 0 && s0 == s1 && s0 == s2 && s0 == s3) {
      atomicAddF(&hg[(size_t)s0 * F + tid],
                 hred[0][tid] + hred[1][tid] + hred[2][tid] + hred[3][tid]);
    } else {
      if (s0 >= 0) atomicAddF(&hg[(size_t)s0 * F + tid], hred[0][tid]);
      if (s1 >= 0) atomicAddF(&hg[(size_t)s1 * F + tid], hred[1][tid]);
      if (s2 >= 0) atomicAddF(&hg[(size_t)s2 * F + tid], hred[2][tid]);
      if (s3 >= 0) atomicAddF(&hg[(size_t)s3 * F + tid], hred[3][tid]);
    }
  }
}

// ---------------- final ----------------
__global__ __launch_bounds__(64) void final_kernel(
    const float* __restrict__ hg1, const int* __restrict__ cnt1,
    const float* __restrict__ hg2, const int* __restrict__ cnt2,
    const float* __restrict__ Wc, const float* __restrict__ bc,
    float* __restrict__ out) {
  __shared__ float v1[F], v2[F];
  int g = blockIdx.x, c = threadIdx.x;
  float ic1 = 1.0f / fmaxf((float)cnt1[g], 1.0f);
  float ic2 = 1.0f / fmaxf((float)cnt2[g], 1.0f);
  for (int i = c; i < F; i += 64) {
    v1[i] = hg1[(size_t)g * F + i] * ic1;
    v2[i] = hg2[(size_t)g * F + i] * ic2;
  }
  __syncthreads();
  float z1 = bc[c], z2 = bc[c];
  for (int k = 0; k < F; ++k) {
    float w = Wc[k * C + c];
    z1 += v1[k] * w;
    z2 += v2[k] * w;
  }
  float d = z1 - z2 + 1e-6f;
  d *= d;
#pragma unroll
  for (int m = 1; m < 64; m <<= 1) d += __shfl_xor(d, m);
  if (c == 0) out[g] = sqrtf(d);
}

extern "C" void kernel_launch(void* const* d_in, const int* in_sizes, int n_in,
                              void* d_out, int out_size, void* d_ws, size_t ws_size,
                              hipStream_t stream) {
  const float* feat1 = (const float*)d_in[0];
  const float* feat2 = (const float*)d_in[1];
  const int* src1 = (const int*)d_in[2];
  const int* dst1 = (const int*)d_in[3];
  const int* gid1 = (const int*)d_in[4];
  const int* src2 = (const int*)d_in[5];
  const int* dst2 = (const int*)d_in[6];
  const int* gid2 = (const int*)d_in[7];
  const float* Wg = (const float*)d_in[8];
  const float* bg = (const float*)d_in[9];
  const float* Wc = (const float*)d_in[10];
  const float* bc = (const float*)d_in[11];
  float* out = (float*)d_out;

  int N = in_sizes[0] / F;
  int E = in_sizes[2];
  int K = (N + 255) >> 8;           // coarse buckets (391 for N=100000)
  if (K > KMAX) return;             // unsupported size: fail loudly

  // ---- workspace layout: zero-init region first ----
  char* w = (char*)d_ws;
  float* hg1 = (float*)w; w += (size_t)G * F * 4;
  float* hg2 = (float*)w; w += (size_t)G * F * 4;
  int* bcntD1 = (int*)w; w += KMAX * 4;
  int* bcntD2 = (int*)w; w += KMAX * 4;
  int* bcntS1 = (int*)w; w += KMAX * 4;
  int* bcntS2 = (int*)w; w += KMAX * 4;
  size_t zbytes = (size_t)(w - (char*)d_ws);
  // non-zeroed scratch:
  __half* aggh1 = (__half*)w; w += (size_t)N * F * 2;
  __half* aggh2 = (__half*)w; w += (size_t)N * F * 2;
  __half* fs1 = (__half*)w; w += (size_t)N * F * 2;
  __half* fs2 = (__half*)w; w += (size_t)N * F * 2;
  unsigned* epkD1 = (unsigned*)w; w += (size_t)E * 4;  // pass1 packed; pass2 rewrites as esrc
  unsigned* epkD2 = (unsigned*)w; w += (size_t)E * 4;
  int* degi1 = (int*)w; w += (size_t)N * 4;
  int* degi2 = (int*)w; w += (size_t)N * 4;
  float* dni1 = (float*)w; w += (size_t)N * 4;
  float* dni2 = (float*)w; w += (size_t)N * 4;
  float* dno1 = (float*)w; w += (size_t)N * 4;
  float* dno2 = (float*)w; w += (size_t)N * 4;
  int* cursor1 = (int*)w; w += (size_t)N * 4;
  int* cursor2 = (int*)w; w += (size_t)N * 4;
  int* cnt1 = (int*)w; w += 128 * 4;
  int* cnt2 = (int*)w; w += 128 * 4;
  int* bstartD1 = (int*)w; w += (KMAX + 4) * 4;
  int* bstartD2 = (int*)w; w += (KMAX + 4) * 4;
  int* bstartS1 = (int*)w; w += (KMAX + 4) * 4;
  int* bstartS2 = (int*)w; w += (KMAX + 4) * 4;
  int* bcurD1 = (int*)w; w += KMAX * 4;
  int* bcurD2 = (int*)w; w += KMAX * 4;
  int* bcurS1 = (int*)w; w += KMAX * 4;
  int* bcurS2 = (int*)w; w += KMAX * 4;
  _Float16* Wt = (_Float16*)w; w += (size_t)F * F * 2;  // swizzled fp16 W
  if ((size_t)(w - (char*)d_ws) > ws_size) return;  // fail loudly (output stays poisoned)

  // epkS (src-count words) aliases aggh1: dead until gather, consumed by pass2c before.
  unsigned* epkS1 = (unsigned*)aggh1;
  unsigned* epkS2 = epkS1 + E;   // 2*E*4 = 12.8 MB <= 25.6 MB (aggh1) ✓

  (void)hipMemsetAsync(d_ws, 0, zbytes, stream);

  wconv_kernel<<<1, 256, 0, stream>>>(Wg, Wt);

  int bhb = (E + BHCH - 1) / BHCH;
  bhist_kernel<<<dim3(bhb, 2), 256, 0, stream>>>(src1, dst1, src2, dst2,
                                                 bcntD1, bcntD2, bcntS1, bcntS2, E, K);
  bscan_kernel<<<4, 512, 0, stream>>>(bcntD1, bcntD2, bcntS1, bcntS2,
                                      bstartD1, bstartD2, bstartS1, bstartS2,
                                      bcurD1, bcurD2, bcurS1, bcurS2, K, E);

  cnt_kernel<<<2, 128, 0, stream>>>(gid1, gid2, cnt1, cnt2, N);

  int p1b = (E + P1CH - 1) / P1CH;
  pass1_kernel<<<dim3(p1b, 2), 256, 0, stream>>>(src1, dst1, src2, dst2,
                                                 bcurD1, bcurD2, bcurS1, bcurS2,
                                                 epkD1, epkD2, epkS1, epkS2, E, K);
  pass2_kernel<<<dim3(K, 2), 256, 0, stream>>>(bstartD1, bstartD2, epkD1, epkD2,
                                               degi1, degi2, dni1, dni2,
                                               cursor1, cursor2, N);
  pass2c_kernel<<<dim3(K, 2), 256, 0, stream>>>(bstartS1, bstartS2, epkS1, epkS2,
                                                dno1, dno2, N);

  // fp16 pre-scaled features (right before gather to maximize L3 residency)
  int fsb = (N * (F / 4) + 255) / 256;
  fscale_kernel<<<dim3(fsb, 2), 256, 0, stream>>>(feat1, feat2, dno1, dno2, fs1, fs2, N);

  // gather per branch sequentially: hot featsc = 25.6 MB -> L3-resident
  int gbr = (N + 7) / 8;
  gather_kernel<<<gbr, 256, 0, stream>>>((const int*)epkD1, cursor1, degi1, fs1, aggh1, N);
  gather_kernel<<<gbr, 256, 0, stream>>>((const int*)epkD2, cursor2, degi2, fs2, aggh2, N);

  int gb = (N + 63) / 64;
  gemm_epi_kernel<<<dim3(gb, 2), 256, 0, stream>>>(
      aggh1, dni1, gid1, hg1, aggh2, dni2, gid2, hg2, Wt, bg, N);

  final_kernel<<<G, 64, 0, stream>>>(hg1, cnt1, hg2, cnt2, Wc, bc, out);
}

// Round 9
// 466.170 us; speedup vs baseline: 13.9665x; 1.1013x over previous
//
#include <hip/hip_runtime.h>
#include <hip/hip_fp16.h>
#include <math.h>

// Problem constants: F=IN_FEATS=H2=128, C=N_CLASSES=64, G=N_GRAPHS=128
#define F 128
#define C 64
#define G 128
#define KMAX 512     // max coarse buckets (N <= 131072)
#define P1CH 8192    // edges per block in pass1
#define CAPB 4608    // fixed stride per coarse bucket (mean 4092 + 8 sigma)

typedef _Float16 f16x8 __attribute__((ext_vector_type(8)));
typedef float f32x4 __attribute__((ext_vector_type(4)));

__device__ __forceinline__ void atomicAddF(float* p, float v) {
  __hip_atomic_fetch_add(p, v, __ATOMIC_RELAXED, __HIP_MEMORY_SCOPE_AGENT);
}

// ---------------- featsc[n][j] = fp16(feat[n][j] * dno[n]) ----------------
__global__ __launch_bounds__(256) void fscale_kernel(
    const float* __restrict__ feat1, const float* __restrict__ feat2,
    const float* __restrict__ dno1, const float* __restrict__ dno2,
    __half* __restrict__ fs1, __half* __restrict__ fs2, int N) {
  const float* feat = blockIdx.y ? feat2 : feat1;
  const float* dno = blockIdx.y ? dno2 : dno1;
  __half* fs = blockIdx.y ? fs2 : fs1;
  int i = blockIdx.x * blockDim.x + threadIdx.x;    // over N*F/4
  if (i >= N * (F / 4)) return;
  int node = i >> 5;                                 // F/4 == 32
  float dn = dno[node];
  float4 v = ((const float4*)feat)[i];
  unsigned short h0 = __half_as_ushort(__float2half(v.x * dn));
  unsigned short h1 = __half_as_ushort(__float2half(v.y * dn));
  unsigned short h2 = __half_as_ushort(__float2half(v.z * dn));
  unsigned short h3 = __half_as_ushort(__float2half(v.w * dn));
  unsigned long long pk = (unsigned long long)h0 | ((unsigned long long)h1 << 16) |
                          ((unsigned long long)h2 << 32) | ((unsigned long long)h3 << 48);
  ((unsigned long long*)fs)[i] = pk;
}

// ---------------- W -> fp16, pre-swizzled into MFMA B-fragment order ----------------
__global__ __launch_bounds__(256) void wconv_kernel(const float* __restrict__ Wg,
                                                    _Float16* __restrict__ Wt) {
  int tid = threadIdx.x;
#pragma unroll
  for (int i = 0; i < 8; ++i) {
    int f = tid + i * 256;          // 0..2047
    int lane = f & 63;
    int ks = (f >> 6) & 3;
    int t = f >> 8;
    int n = t * 16 + (lane & 15);
    int k0 = ks * 32 + ((lane >> 4) << 3);
    f16x8 v;
#pragma unroll
    for (int j = 0; j < 8; ++j) v[j] = (_Float16)Wg[(k0 + j) * F + n];
    ((f16x8*)Wt)[f] = v;
  }
}

// ---------------- per-graph node counts via binary search (gid sorted) ----------------
__global__ __launch_bounds__(128) void cnt_kernel(const int* __restrict__ gid1,
                                                  const int* __restrict__ gid2,
                                                  int* __restrict__ cnt1,
                                                  int* __restrict__ cnt2, int N) {
  const int* gid = blockIdx.x ? gid2 : gid1;
  int* cnt = blockIdx.x ? cnt2 : cnt1;
  int g = threadIdx.x;
  int lo = 0, hi = N;
  while (lo < hi) { int m = (lo + hi) >> 1; if (gid[m] < g) lo = m + 1; else hi = m; }
  int lo2 = lo, hi2 = N;
  while (lo2 < hi2) { int m = (lo2 + hi2) >> 1; if (gid[m] <= g) lo2 = m + 1; else hi2 = m; }
  cnt[g] = lo2 - lo;
}

// ---------------- pass1: block-local counting sort -> coalesced bucket-run flush --------
// epkD[k*CAPB + ...] words (dst&255)<<24|src ; epkS8[k*CAPB + ...] bytes (src&255).
// bcntD/bcntS (zero-init) accumulate global per-bucket totals via reservation atomics.
__global__ __launch_bounds__(256) void pass1_kernel(
    const int* __restrict__ src1, const int* __restrict__ dst1,
    const int* __restrict__ src2, const int* __restrict__ dst2,
    int* __restrict__ bcntD1, int* __restrict__ bcntD2,
    int* __restrict__ bcntS1, int* __restrict__ bcntS2,
    unsigned* __restrict__ epkD1, unsigned* __restrict__ epkD2,
    unsigned char* __restrict__ epkS81, unsigned char* __restrict__ epkS82,
    int E, int K) {
  const int* src = blockIdx.y ? src2 : src1;
  const int* dst = blockIdx.y ? dst2 : dst1;
  int* bcntD = blockIdx.y ? bcntD2 : bcntD1;
  int* bcntS = blockIdx.y ? bcntS2 : bcntS1;
  unsigned* epkD = blockIdx.y ? epkD2 : epkD1;
  unsigned char* epkS8 = blockIdx.y ? epkS82 : epkS81;

  __shared__ int cntD[KMAX], resD[KMAX], baseD[KMAX], curD[KMAX];
  __shared__ int cntS[KMAX], resS[KMAX], baseS[KMAX], curS[KMAX];
  __shared__ unsigned stageD[P1CH];
  __shared__ unsigned char stageS[P1CH];

  int t = threadIdx.x;
  int lane = t & 63;
  int wv = t >> 6;

  for (int k = t; k < K; k += 256) { cntD[k] = 0; cntS[k] = 0; }
  __syncthreads();

  int e0 = blockIdx.x * P1CH;
  int e1 = e0 + P1CH; if (e1 > E) e1 = E;
  int M = e1 - e0;
  for (int i = e0 + t; i < e1; i += 256) {
    atomicAdd(&cntD[dst[i] >> 8], 1);
    atomicAdd(&cntS[src[i] >> 8], 1);
  }
  __syncthreads();

  // block-exclusive scans: wave 0 scans cntD, wave 1 scans cntS
  if (wv == 0) {
    int carry = 0;
    for (int b0 = 0; b0 < K; b0 += 64) {
      int k = b0 + lane;
      int v = (k < K) ? cntD[k] : 0;
      int x = v;
#pragma unroll
      for (int off = 1; off < 64; off <<= 1) {
        int y = __shfl_up(x, off);
        if (lane >= off) x += y;
      }
      if (k < K) baseD[k] = carry + x - v;
      carry += __shfl(x, 63);
    }
  } else if (wv == 1) {
    int carry = 0;
    for (int b0 = 0; b0 < K; b0 += 64) {
      int k = b0 + lane;
      int v = (k < K) ? cntS[k] : 0;
      int x = v;
#pragma unroll
      for (int off = 1; off < 64; off <<= 1) {
        int y = __shfl_up(x, off);
        if (lane >= off) x += y;
      }
      if (k < K) baseS[k] = carry + x - v;
      carry += __shfl(x, 63);
    }
  }
  __syncthreads();

  // reserve global runs; init phase-1 cursors
  for (int k = t; k < K; k += 256) {
    int c = cntD[k];
    resD[k] = c ? atomicAdd(&bcntD[k], c) : 0;
    int c2 = cntS[k];
    resS[k] = c2 ? atomicAdd(&bcntS[k], c2) : 0;
    curD[k] = baseD[k];
    curS[k] = baseS[k];
  }
  __syncthreads();

  // stage into LDS, bucket-sorted
  for (int i = e0 + t; i < e1; i += 256) {
    int d = dst[i];
    int s = src[i];
    int p = atomicAdd(&curD[d >> 8], 1);
    stageD[p] = ((unsigned)(d & 255) << 24) | (unsigned)s;
    int q = atomicAdd(&curS[s >> 8], 1);
    stageS[q] = (unsigned char)(s & 255);
  }
  __syncthreads();

  // flush D: consecutive i -> consecutive global addresses within runs
  for (int i = t; i < M; i += 256) {
    int lo = 0, hi = K - 1;
    while (lo < hi) { int mid = (lo + hi + 1) >> 1; if (baseD[mid] <= i) lo = mid; else hi = mid - 1; }
    int off = i - baseD[lo];
    unsigned pos = (unsigned)(resD[lo] + off);
    if (pos < CAPB) epkD[(size_t)lo * CAPB + pos] = stageD[i];
  }
  // flush S (bytes)
  for (int i = t; i < M; i += 256) {
    int lo = 0, hi = K - 1;
    while (lo < hi) { int mid = (lo + hi + 1) >> 1; if (baseS[mid] <= i) lo = mid; else hi = mid - 1; }
    int off = i - baseS[lo];
    unsigned pos = (unsigned)(resS[lo] + off);
    if (pos < CAPB) epkS8[(size_t)lo * CAPB + pos] = stageS[i];
  }
}

// ---------------- pass2: dst-bucket fine sort; emits degi/cursor + esrc in-place ------
__global__ __launch_bounds__(256) void pass2_kernel(
    const int* __restrict__ bcntD1, const int* __restrict__ bcntD2,
    unsigned* __restrict__ epk1, unsigned* __restrict__ epk2,
    int* __restrict__ degi1, int* __restrict__ degi2,
    int* __restrict__ cursor1, int* __restrict__ cursor2, int N) {
  const int* bcntD = blockIdx.y ? bcntD2 : bcntD1;
  unsigned* epk = blockIdx.y ? epk2 : epk1;   // also the esrc output (in-place)
  int* degi = blockIdx.y ? degi2 : degi1;
  int* cursor = blockIdx.y ? cursor2 : cursor1;

  __shared__ unsigned pk[CAPB];
  __shared__ int lcnt[256];
  __shared__ int lcur[256];

  int b = blockIdx.x;
  int t = threadIdx.x;
  int s0 = b * CAPB;
  int M = bcntD[b]; if (M > CAPB) M = CAPB;

  lcnt[t] = 0;
  for (int e = t; e < M; e += 256) pk[e] = epk[s0 + e];
  __syncthreads();
  for (int e = t; e < M; e += 256) atomicAdd(&lcnt[pk[e] >> 24], 1);
  __syncthreads();

  int v = lcnt[t];
  lcur[t] = v;
  __syncthreads();
  for (int off = 1; off < 256; off <<= 1) {
    int x = (t >= off) ? lcur[t - off] : 0;
    __syncthreads();
    lcur[t] += x;
    __syncthreads();
  }
  int excl = lcur[t] - v;
  int startp = s0 + excl;
  int node = (b << 8) + t;
  if (node < N) {
    degi[node] = v;
    cursor[node] = startp;
  }
  __syncthreads();
  lcur[t] = startp;
  __syncthreads();
  for (int e = t; e < M; e += 256) {
    unsigned p = pk[e];
    int dl = p >> 24;
    int pos = atomicAdd(&lcur[dl], 1);
    epk[pos] = p & 0xFFFFFFu;   // esrc value (node id < 2^17)
  }
}

// ---------------- pass2c: src-bucket byte histogram -> dno ----------------
__global__ __launch_bounds__(256) void pass2c_kernel(
    const int* __restrict__ bcntS1, const int* __restrict__ bcntS2,
    const unsigned char* __restrict__ epk1, const unsigned char* __restrict__ epk2,
    float* __restrict__ dno1, float* __restrict__ dno2, int N) {
  const int* bcntS = blockIdx.y ? bcntS2 : bcntS1;
  const unsigned char* epk = blockIdx.y ? epk2 : epk1;
  float* dno = blockIdx.y ? dno2 : dno1;

  __shared__ int lcnt[256];
  int b = blockIdx.x;
  int t = threadIdx.x;
  int s0 = b * CAPB;
  int M = bcntS[b]; if (M > CAPB) M = CAPB;
  lcnt[t] = 0;
  __syncthreads();
  for (int e = t; e < M; e += 256)
    atomicAdd(&lcnt[epk[s0 + e]], 1);
  __syncthreads();
  int node = (b << 8) + t;
  if (node < N) {
    int a = lcnt[t]; if (a < 1) a = 1;
    dno[node] = 1.0f / sqrtf((float)a);
  }
}

// ---------------- gather-reduce: agg[d] = sum over in-edges of featsc[s] (fp16 rows) -------
__global__ __launch_bounds__(256) void gather_kernel(
    const int* __restrict__ esrc1, const int* __restrict__ cursor1,
    const int* __restrict__ degi1, const __half* __restrict__ fs1,
    __half* __restrict__ aggh1,
    const int* __restrict__ esrc2, const int* __restrict__ cursor2,
    const int* __restrict__ degi2, const __half* __restrict__ fs2,
    __half* __restrict__ aggh2, int N) {
  const int* esrc = blockIdx.y ? esrc2 : esrc1;
  const int* cursor = blockIdx.y ? cursor2 : cursor1;
  const int* degi = blockIdx.y ? degi2 : degi1;
  const __half* featsc = blockIdx.y ? fs2 : fs1;
  __half* aggh = blockIdx.y ? aggh2 : aggh1;

  int node = blockIdx.x * 8 + (threadIdx.x >> 5);
  int l = threadIdx.x & 31;
  if (node >= N) return;
  int cnt = degi[node];
  int start = cursor[node];
  float4 acc = {0.f, 0.f, 0.f, 0.f};
  for (int j0 = 0; j0 < cnt; j0 += 32) {
    int nb = cnt - j0; if (nb > 32) nb = 32;
    int myi = (l < nb) ? __builtin_nontemporal_load(&esrc[start + j0 + l]) : 0;
#pragma unroll 4
    for (int k = 0; k < nb; ++k) {
      int s = __shfl(myi, k, 32);
      unsigned long long rv = ((const unsigned long long*)(featsc + (size_t)s * F))[l];
      union { unsigned long long u; __half2 h[2]; } U; U.u = rv;
      float2 f0 = __half22float2(U.h[0]);
      float2 f1 = __half22float2(U.h[1]);
      acc.x += f0.x; acc.y += f0.y; acc.z += f1.x; acc.w += f1.y;
    }
  }
  unsigned long long o =
      (unsigned long long)__half_as_ushort(__float2half(acc.x)) |
      ((unsigned long long)__half_as_ushort(__float2half(acc.y)) << 16) |
      ((unsigned long long)__half_as_ushort(__float2half(acc.z)) << 32) |
      ((unsigned long long)__half_as_ushort(__float2half(acc.w)) << 48);
  __builtin_nontemporal_store(o, (unsigned long long*)(aggh + (size_t)node * F) + l);
}

// ---------------- MFMA gemm + epilogue ----------------
__global__ __launch_bounds__(256) void gemm_epi_kernel(
    const __half* __restrict__ agg1, const int* __restrict__ degi1,
    const int* __restrict__ gid1, float* __restrict__ hg1,
    const __half* __restrict__ agg2, const int* __restrict__ degi2,
    const int* __restrict__ gid2, float* __restrict__ hg2,
    const _Float16* __restrict__ Wt, const float* __restrict__ bg, int N) {
  const __half* agg = blockIdx.y ? agg2 : agg1;
  const int* degi = blockIdx.y ? degi2 : degi1;
  const int* gid = blockIdx.y ? gid2 : gid1;
  float* hg = blockIdx.y ? hg2 : hg1;

  __shared__ __align__(16) _Float16 Wl[16384];   // 32KB, B-fragment order
  __shared__ float hred[4][F];
  __shared__ int sgid[4];

  int tid = threadIdx.x;
  int wv = tid >> 6;
  int lane = tid & 63;
  int ln = lane & 15;
  int quad = lane >> 4;

  {
    const f16x8* src = (const f16x8*)Wt;
    f16x8* dst = (f16x8*)Wl;
#pragma unroll
    for (int i = 0; i < 8; ++i) dst[tid + i * 256] = src[tid + i * 256];
  }
  __syncthreads();

  int rbase = (blockIdx.x * 4 + wv) * 16;
  bool wave_active = rbase < N;

  int arow = rbase + ln; if (arow >= N) arow = N - 1;
  const _Float16* arow_p = (const _Float16*)(agg + (size_t)arow * F);
  f16x8 a[4];
#pragma unroll
  for (int ks = 0; ks < 4; ++ks)
    a[ks] = *(const f16x8*)(arow_p + ks * 32 + quad * 8);

  f32x4 acc[8];
#pragma unroll
  for (int t = 0; t < 8; ++t) acc[t] = (f32x4){0.f, 0.f, 0.f, 0.f};

#pragma unroll
  for (int t = 0; t < 8; ++t) {
#pragma unroll
    for (int ks = 0; ks < 4; ++ks) {
      f16x8 b = *(const f16x8*)&Wl[(((t << 2) + ks) * 64 + lane) * 8];
      acc[t] = __builtin_amdgcn_mfma_f32_16x16x32_f16(a[ks], b, acc[t], 0, 0, 0);
    }
  }

  float dnr[4]; int gg[4]; bool valid[4];
#pragma unroll
  for (int r = 0; r < 4; ++r) {
    int row = rbase + quad * 4 + r;
    valid[r] = row < N;
    int rc = valid[r] ? row : (N - 1);
    int dv = degi[rc]; if (dv < 1) dv = 1;
    dnr[r] = 1.0f / sqrtf((float)dv);
    gg[r] = gid[rc];
  }
  float bb[8];
#pragma unroll
  for (int t = 0; t < 8; ++t) bb[t] = bg[t * 16 + ln];

  float y[8][4], ssq[4];
#pragma unroll
  for (int r = 0; r < 4; ++r) ssq[r] = 0.f;
#pragma unroll
  for (int t = 0; t < 8; ++t) {
#pragma unroll
    for (int r = 0; r < 4; ++r) {
      float v = acc[t][r] * dnr[r] + bb[t];
      y[t][r] = v;
      ssq[r] += v * v;
    }
  }
#pragma unroll
  for (int m = 1; m < 16; m <<= 1) {
#pragma unroll
    for (int r = 0; r < 4; ++r) ssq[r] += __shfl_xor(ssq[r], m);
  }
  float u[8][4];
#pragma unroll
  for (int r = 0; r < 4; ++r) {
    float inv = 1.0f / fmaxf(sqrtf(ssq[r]), 1e-12f);
#pragma unroll
    for (int t = 0; t < 8; ++t) {
      float s = 1.0f / (1.0f + expf(-y[t][r] * inv));  // relu(sigmoid) == sigmoid
      u[t][r] = valid[r] ? s : 0.0f;
    }
  }

  int rlast = rbase + 15; if (rlast >= N) rlast = N - 1;
  bool uniform = wave_active && (rbase + 15 < N) && (gid[rbase] == gid[rlast]);
  if (uniform) {
    float cs[8];
#pragma unroll
    for (int t = 0; t < 8; ++t) {
      cs[t] = u[t][0] + u[t][1] + u[t][2] + u[t][3];
      cs[t] += __shfl_xor(cs[t], 16);
      cs[t] += __shfl_xor(cs[t], 32);
    }
    if (lane == 0) sgid[wv] = gid[rbase];
    if (lane < 16) {
#pragma unroll
      for (int t = 0; t < 8; ++t) hred[wv][t * 16 + lane] = cs[t];
    }
  } else {
    if (lane == 0) sgid[wv] = -1;
    if (wave_active) {
#pragma unroll
      for (int r = 0; r < 4; ++r) {
        if (!valid[r]) continue;
#pragma unroll
        for (int t = 0; t < 8; ++t)
          atomicAddF(&hg[(size_t)gg[r] * F + t * 16 + ln], u[t][r]);
      }
    }
  }
  __syncthreads();
  if (tid < F) {
    int s0 = sgid[0], s1 = sgid[1], s2 = sgid[2], s3 = sgid[3];
    if (s0 >= 0 && s0 == s1 && s0 == s2 && s0 == s3) {
      atomicAddF(&hg[(size_t)s0 * F + tid],
                 hred[0][tid] + hred[1][tid] + hred[2][tid] + hred[3][tid]);
    } else {
      if (s0 >= 0) atomicAddF(&hg[(size_t)s0 * F + tid], hred[0][tid]);
      if (s1 >= 0) atomicAddF(&hg[(size_t)s1 * F + tid], hred[1][tid]);
      if (s2 >= 0) atomicAddF(&hg[(size_t)s2 * F + tid], hred[2][tid]);
      if (s3 >= 0) atomicAddF(&hg[(size_t)s3 * F + tid], hred[3][tid]);
    }
  }
}

// ---------------- final ----------------
__global__ __launch_bounds__(64) void final_kernel(
    const float* __restrict__ hg1, const int* __restrict__ cnt1,
    const float* __restrict__ hg2, const int* __restrict__ cnt2,
    const float* __restrict__ Wc, const float* __restrict__ bc,
    float* __restrict__ out) {
  __shared__ float v1[F], v2[F];
  int g = blockIdx.x, c = threadIdx.x;
  float ic1 = 1.0f / fmaxf((float)cnt1[g], 1.0f);
  float ic2 = 1.0f / fmaxf((float)cnt2[g], 1.0f);
  for (int i = c; i < F; i += 64) {
    v1[i] = hg1[(size_t)g * F + i] * ic1;
    v2[i] = hg2[(size_t)g * F + i] * ic2;
  }
  __syncthreads();
  float z1 = bc[c], z2 = bc[c];
  for (int k = 0; k < F; ++k) {
    float w = Wc[k * C + c];
    z1 += v1[k] * w;
    z2 += v2[k] * w;
  }
  float d = z1 - z2 + 1e-6f;
  d *= d;
#pragma unroll
  for (int m = 1; m < 64; m <<= 1) d += __shfl_xor(d, m);
  if (c == 0) out[g] = sqrtf(d);
}

extern "C" void kernel_launch(void* const* d_in, const int* in_sizes, int n_in,
                              void* d_out, int out_size, void* d_ws, size_t ws_size,
                              hipStream_t stream) {
  const float* feat1 = (const float*)d_in[0];
  const float* feat2 = (const float*)d_in[1];
  const int* src1 = (const int*)d_in[2];
  const int* dst1 = (const int*)d_in[3];
  const int* gid1 = (const int*)d_in[4];
  const int* src2 = (const int*)d_in[5];
  const int* dst2 = (const int*)d_in[6];
  const int* gid2 = (const int*)d_in[7];
  const float* Wg = (const float*)d_in[8];
  const float* bg = (const float*)d_in[9];
  const float* Wc = (const float*)d_in[10];
  const float* bc = (const float*)d_in[11];
  float* out = (float*)d_out;

  int N = in_sizes[0] / F;
  int E = in_sizes[2];
  int K = (N + 255) >> 8;           // coarse buckets (391 for N=100000)
  if (K > KMAX) return;             // unsupported size: fail loudly

  // ---- workspace layout: zero-init region first ----
  char* w = (char*)d_ws;
  float* hg1 = (float*)w; w += (size_t)G * F * 4;
  float* hg2 = (float*)w; w += (size_t)G * F * 4;
  int* bcntD1 = (int*)w; w += KMAX * 4;
  int* bcntD2 = (int*)w; w += KMAX * 4;
  int* bcntS1 = (int*)w; w += KMAX * 4;
  int* bcntS2 = (int*)w; w += KMAX * 4;
  size_t zbytes = (size_t)(w - (char*)d_ws);
  // non-zeroed scratch:
  __half* aggh1 = (__half*)w; w += (size_t)N * F * 2;
  __half* aggh2 = (__half*)w; w += (size_t)N * F * 2;
  __half* fs1 = (__half*)w; w += (size_t)N * F * 2;
  __half* fs2 = (__half*)w; w += (size_t)N * F * 2;
  unsigned* epkD1 = (unsigned*)w; w += (size_t)K * CAPB * 4;  // pass1; pass2 rewrites as esrc
  unsigned* epkD2 = (unsigned*)w; w += (size_t)K * CAPB * 4;
  int* degi1 = (int*)w; w += (size_t)N * 4;
  int* degi2 = (int*)w; w += (size_t)N * 4;
  float* dno1 = (float*)w; w += (size_t)N * 4;
  float* dno2 = (float*)w; w += (size_t)N * 4;
  int* cursor1 = (int*)w; w += (size_t)N * 4;
  int* cursor2 = (int*)w; w += (size_t)N * 4;
  int* cnt1 = (int*)w; w += 128 * 4;
  int* cnt2 = (int*)w; w += 128 * 4;
  _Float16* Wt = (_Float16*)w; w += (size_t)F * F * 2;  // swizzled fp16 W
  if ((size_t)(w - (char*)d_ws) > ws_size) return;  // fail loudly (output stays poisoned)

  // epkS byte arrays alias aggh1: dead until gather, consumed by pass2c before.
  unsigned char* epkS81 = (unsigned char*)aggh1;
  unsigned char* epkS82 = epkS81 + (size_t)K * CAPB;  // 2*K*CAPB = 3.6 MB <= 25.6 MB ✓

  (void)hipMemsetAsync(d_ws, 0, zbytes, stream);

  wconv_kernel<<<1, 256, 0, stream>>>(Wg, Wt);
  cnt_kernel<<<2, 128, 0, stream>>>(gid1, gid2, cnt1, cnt2, N);

  int p1b = (E + P1CH - 1) / P1CH;
  pass1_kernel<<<dim3(p1b, 2), 256, 0, stream>>>(
      src1, dst1, src2, dst2, bcntD1, bcntD2, bcntS1, bcntS2,
      epkD1, epkD2, epkS81, epkS82, E, K);
  pass2_kernel<<<dim3(K, 2), 256, 0, stream>>>(bcntD1, bcntD2, epkD1, epkD2,
                                               degi1, degi2, cursor1, cursor2, N);
  pass2c_kernel<<<dim3(K, 2), 256, 0, stream>>>(bcntS1, bcntS2, epkS81, epkS82,
                                                dno1, dno2, N);

  // fp16 pre-scaled features
  int fsb = (N * (F / 4) + 255) / 256;
  fscale_kernel<<<dim3(fsb, 2), 256, 0, stream>>>(feat1, feat2, dno1, dno2, fs1, fs2, N);

  // both branches in one dispatch: hot featsc = 51.2 MB, L3-resident
  int gbr = (N + 7) / 8;
  gather_kernel<<<dim3(gbr, 2), 256, 0, stream>>>(
      (const int*)epkD1, cursor1, degi1, fs1, aggh1,
      (const int*)epkD2, cursor2, degi2, fs2, aggh2, N);

  int gb = (N + 63) / 64;
  gemm_epi_kernel<<<dim3(gb, 2), 256, 0, stream>>>(
      aggh1, degi1, gid1, hg1, aggh2, degi2, gid2, hg2, Wt, bg, N);

  final_kernel<<<G, 64, 0, stream>>>(hg1, cnt1, hg2, cnt2, Wc, bc, out);
}